// Round 1
// baseline (196.988 us; speedup 1.0000x reference)
//
#include <hip/hip_runtime.h>
#include <stdint.h>

// ---------------------------------------------------------------------------
// Sizes (fixed by the problem)
// ---------------------------------------------------------------------------
#define BB    4096
#define KS    8
#define PP    768
#define SLOT  256
#define HID   256
#define NC    512
#define BKROWS (BB*KS)          // 32768
typedef unsigned short u16;
typedef short bf16x8 __attribute__((ext_vector_type(8)));
typedef float f32x4  __attribute__((ext_vector_type(4)));

__device__ __forceinline__ u16 f2bf(float x) {
  union { float f; uint32_t u; } v; v.f = x;
  return (u16)((v.u + 0x7FFFu + ((v.u >> 16) & 1u)) >> 16);
}

__device__ __forceinline__ void gload_lds16(u16* ldst, const u16* gsrc) {
  __builtin_amdgcn_global_load_lds(
      (const __attribute__((address_space(1))) void*)gsrc,
      (__attribute__((address_space(3))) void*)ldst, 16, 0, 0);
}

// ---------------------------------------------------------------------------
// GEMM: C[M,N] = A_bf16[M,K] @ Bt_bf16[N,K]^T  (+ epilogue)
// BM=BN=128, BK=64, 256 threads = 4 waves (2x2), wave tile 64x64 (4x4 frags)
// LDS tiles linear-dest via global_load_lds; XOR swizzle applied on the
// global SOURCE address and again on the ds_read (involution) -> conflict-free.
// EPI: 0 = store f32
//      1 = +bias[col], store bf16
//      2 = store bf16
//      3 = +bias[col], store f32
//      4 = +tadd[(row>>3)*ldo+col], store f32
// ---------------------------------------------------------------------------
template<int EPI>
__global__ __launch_bounds__(256) void gemm_bt(
    const u16* __restrict__ A0, const u16* __restrict__ A1, int lda,
    const u16* __restrict__ B0, const u16* __restrict__ B1, int ldb,
    const float* __restrict__ bias0, const float* __restrict__ bias1,
    const float* __restrict__ t0, const float* __restrict__ t1,
    void* __restrict__ out0, void* __restrict__ out1, int ldo,
    int K)
{
  const int z = blockIdx.z;
  const u16*   A    = z ? A1 : A0;
  const u16*   B    = z ? B1 : B0;
  const float* bias = z ? bias1 : bias0;
  const float* tadd = z ? t1 : t0;
  void*        out  = z ? out1 : out0;

  __shared__ u16 lsA[128 * 64];
  __shared__ u16 lsB[128 * 64];

  const int tid  = threadIdx.x;
  const int w    = tid >> 6;
  const int lane = tid & 63;
  const int wm   = w >> 1, wn = w & 1;
  const int rl   = lane >> 4, cl = lane & 15;
  const int blockRow = blockIdx.x * 128;
  const int blockCol = blockIdx.y * 128;

  f32x4 acc[4][4];
  const f32x4 zero = {0.f, 0.f, 0.f, 0.f};
#pragma unroll
  for (int i = 0; i < 4; ++i)
#pragma unroll
    for (int j = 0; j < 4; ++j) acc[i][j] = zero;

  const u16* Ablk = A + (size_t)blockRow * lda;
  const u16* Bblk = B + (size_t)blockCol * ldb;

  for (int k0 = 0; k0 < K; k0 += 64) {
    // stage 128x64 bf16 tiles of A and Bt (16 KiB each)
#pragma unroll
    for (int i = 0; i < 4; ++i) {
      int seg   = i * 4 + w;             // 1 KiB wave segment
      int off16 = seg * 64 + lane;       // 16B-unit index in tile
      int row   = off16 >> 3;            // 8 chunks (of 8 bf16) per row
      int chunk = (off16 & 7) ^ (row & 7);   // inverse-swizzled source
      gload_lds16(lsA + seg * 512, Ablk + (size_t)row * lda + k0 + chunk * 8);
      gload_lds16(lsB + seg * 512, Bblk + (size_t)row * ldb + k0 + chunk * 8);
    }
    __syncthreads();   // compiler drains vmcnt before s_barrier

#pragma unroll
    for (int ks = 0; ks < 2; ++ks) {
      bf16x8 aF[4], bF[4];
#pragma unroll
      for (int f = 0; f < 4; ++f) {
        int r  = wm * 64 + f * 16 + cl;
        int ca = ((ks * 4 + rl) ^ (r & 7)) * 8;
        aF[f] = *(const bf16x8*)(lsA + r * 64 + ca);
        int rn = wn * 64 + f * 16 + cl;
        int cb = ((ks * 4 + rl) ^ (rn & 7)) * 8;
        bF[f] = *(const bf16x8*)(lsB + rn * 64 + cb);
      }
#pragma unroll
      for (int fm = 0; fm < 4; ++fm)
#pragma unroll
        for (int fn = 0; fn < 4; ++fn)
          acc[fm][fn] = __builtin_amdgcn_mfma_f32_16x16x32_bf16(
              aF[fm], bF[fn], acc[fm][fn], 0, 0, 0);
    }
    __syncthreads();
  }

  // epilogue: D row = (lane>>4)*4 + reg, col = lane&15   [m89-verified]
#pragma unroll
  for (int fm = 0; fm < 4; ++fm) {
#pragma unroll
    for (int fn = 0; fn < 4; ++fn) {
      f32x4 v = acc[fm][fn];
#pragma unroll
      for (int r = 0; r < 4; ++r) {
        int grow = blockRow + wm * 64 + fm * 16 + rl * 4 + r;
        int gcol = blockCol + wn * 64 + fn * 16 + cl;
        float x = v[r];
        if constexpr (EPI == 0) {
          ((float*)out)[(size_t)grow * ldo + gcol] = x;
        } else if constexpr (EPI == 1) {
          x += bias[gcol];
          ((u16*)out)[(size_t)grow * ldo + gcol] = f2bf(x);
        } else if constexpr (EPI == 2) {
          ((u16*)out)[(size_t)grow * ldo + gcol] = f2bf(x);
        } else if constexpr (EPI == 3) {
          x += bias[gcol];
          ((float*)out)[(size_t)grow * ldo + gcol] = x;
        } else if constexpr (EPI == 4) {
          x += tadd[(size_t)(grow >> 3) * ldo + gcol];
          ((float*)out)[(size_t)grow * ldo + gcol] = x;
        }
      }
    }
  }
}

// ---------------------------------------------------------------------------
// prep kernels
// ---------------------------------------------------------------------------
__global__ __launch_bounds__(256) void cvt_bf16(const float* __restrict__ in,
                                                u16* __restrict__ outp, int n4) {
  int i = blockIdx.x * 256 + threadIdx.x;
  if (i < n4) {
    float4 v = ((const float4*)in)[i];
    ushort4 o;
    o.x = f2bf(v.x); o.y = f2bf(v.y); o.z = f2bf(v.z); o.w = f2bf(v.w);
    ((ushort4*)outp)[i] = o;
  }
}

// out[c][r] = bf16(in[r][c]);  R,C multiples of 32
__global__ __launch_bounds__(256) void transpose_cvt(const float* __restrict__ in,
                                                     u16* __restrict__ outp,
                                                     int R, int C) {
  __shared__ float tile[32][33];
  int tc = blockIdx.x * 32, tr = blockIdx.y * 32;
  int lx = threadIdx.x & 31, ly = threadIdx.x >> 5;   // ly: 0..7
#pragma unroll
  for (int i = 0; i < 32; i += 8)
    tile[ly + i][lx] = in[(size_t)(tr + ly + i) * C + tc + lx];
  __syncthreads();
#pragma unroll
  for (int i = 0; i < 32; i += 8)
    outp[(size_t)(tc + ly + i) * R + tr + lx] = f2bf(tile[lx][ly + i]);
}

__global__ void concat_bias(const float* __restrict__ a, const float* __restrict__ b,
                            float* __restrict__ outp, int n) {
  int i = blockIdx.x * 256 + threadIdx.x;
  if (i < n) { outp[i] = a[i]; outp[n + i] = b[i]; }
}

// ---------------------------------------------------------------------------
// softmax over rows of 512 (scores are UNSCALED; alpha folded in here)
// one wave per row, 8 f32 per lane
// ---------------------------------------------------------------------------
__global__ __launch_bounds__(256) void softmax_rows(const float* __restrict__ S,
                                                    u16* __restrict__ Pp) {
  int w = threadIdx.x >> 6, lane = threadIdx.x & 63;
  size_t row = (size_t)blockIdx.x * 4 + w;
  const float* src = S + row * 512 + lane * 8;
  float4 v0 = *(const float4*)src;
  float4 v1 = *(const float4*)(src + 4);
  float vv[8] = {v0.x, v0.y, v0.z, v0.w, v1.x, v1.y, v1.z, v1.w};
  float m = vv[0];
#pragma unroll
  for (int j = 1; j < 8; ++j) m = fmaxf(m, vv[j]);
#pragma unroll
  for (int o = 32; o; o >>= 1) m = fmaxf(m, __shfl_xor(m, o));
  const float alpha = 0.03608439182435161f;   // 1/sqrt(768)
  float e[8], s = 0.f;
#pragma unroll
  for (int j = 0; j < 8; ++j) { e[j] = __expf((vv[j] - m) * alpha); s += e[j]; }
#pragma unroll
  for (int o = 32; o; o >>= 1) s += __shfl_xor(s, o);
  float inv = 1.f / s;
  union { u16 u[8]; uint4 q; } ou;
#pragma unroll
  for (int j = 0; j < 8; ++j) ou.u[j] = f2bf(e[j] * inv);
  *(uint4*)(Pp + row * 512 + lane * 8) = ou.q;
}

// ---------------------------------------------------------------------------
// LayerNorm(256) * g + bt, ReLU, -> bf16.  One wave per row, 4 f32 per lane.
// Hraw/Hout are [2][32768][256] contiguous; z selects params.
// ---------------------------------------------------------------------------
__global__ __launch_bounds__(256) void ln_relu(
    const float* __restrict__ Hraw,
    const float* __restrict__ g0, const float* __restrict__ g1,
    const float* __restrict__ bt0, const float* __restrict__ bt1,
    u16* __restrict__ Hout) {
  int z = blockIdx.z;
  const float* g  = z ? g1 : g0;
  const float* bt = z ? bt1 : bt0;
  int w = threadIdx.x >> 6, lane = threadIdx.x & 63;
  size_t row = (size_t)z * BKROWS + (size_t)blockIdx.x * 4 + w;
  const float* src = Hraw + row * 256 + lane * 4;
  float4 x = *(const float4*)src;
  float s = x.x + x.y + x.z + x.w;
  float q = x.x * x.x + x.y * x.y + x.z * x.z + x.w * x.w;
#pragma unroll
  for (int o = 32; o; o >>= 1) { s += __shfl_xor(s, o); q += __shfl_xor(q, o); }
  float mean = s * (1.f / 256.f);
  float var  = q * (1.f / 256.f) - mean * mean;
  float rs   = rsqrtf(var + 1e-5f);
  int c = lane * 4;
  ushort4 o4;
  o4.x = f2bf(fmaxf((x.x - mean) * rs * g[c + 0] + bt[c + 0], 0.f));
  o4.y = f2bf(fmaxf((x.y - mean) * rs * g[c + 1] + bt[c + 1], 0.f));
  o4.z = f2bf(fmaxf((x.z - mean) * rs * g[c + 2] + bt[c + 2], 0.f));
  o4.w = f2bf(fmaxf((x.w - mean) * rs * g[c + 3] + bt[c + 3], 0.f));
  *(ushort4*)(Hout + row * 256 + lane * 4) = o4;
}

// ---------------------------------------------------------------------------
// out = slots + gp * gu   (all f32, flat 8.4M elements, 4/thread)
// ---------------------------------------------------------------------------
__global__ __launch_bounds__(256) void combine(const float* __restrict__ slots,
                                               const float* __restrict__ gp,
                                               const float* __restrict__ gu,
                                               float* __restrict__ outp) {
  size_t i = ((size_t)blockIdx.x * 256 + threadIdx.x) * 4;
  float4 a = *(const float4*)(slots + i);
  float4 p = *(const float4*)(gp + i);
  float4 u = *(const float4*)(gu + i);
  float4 o;
  o.x = a.x + p.x * u.x; o.y = a.y + p.y * u.y;
  o.z = a.z + p.z * u.z; o.w = a.w + p.w * u.w;
  *(float4*)(outp + i) = o;
}

// ---------------------------------------------------------------------------
// host launcher
// ---------------------------------------------------------------------------
extern "C" void kernel_launch(void* const* d_in, const int* in_sizes, int n_in,
                              void* d_out, int out_size, void* d_ws, size_t ws_size,
                              hipStream_t stream) {
  const float* inst  = (const float*)d_in[0];
  const float* slots = (const float*)d_in[1];
  const float* Wfc   = (const float*)d_in[2];
  const float* bfc   = (const float*)d_in[3];
  const float* Wfp   = (const float*)d_in[4];
  const float* bfp   = (const float*)d_in[5];
  const float* Kc    = (const float*)d_in[6];
  const float* Vc    = (const float*)d_in[7];
  const float* Kp    = (const float*)d_in[8];
  const float* Vp    = (const float*)d_in[9];
  const float* pW1   = (const float*)d_in[10];
  const float* pb1   = (const float*)d_in[11];
  const float* pg    = (const float*)d_in[12];
  const float* pbt   = (const float*)d_in[13];
  const float* pW2   = (const float*)d_in[14];
  const float* pb2   = (const float*)d_in[15];
  const float* uW1   = (const float*)d_in[16];
  const float* ub1   = (const float*)d_in[17];
  const float* ug    = (const float*)d_in[18];
  const float* ubt   = (const float*)d_in[19];
  const float* uW2   = (const float*)d_in[20];
  const float* ub2   = (const float*)d_in[21];
  float* out = (float*)d_out;
  char*  ws  = (char*)d_ws;

  // ---- workspace layout (bytes, all 256-aligned) ----
  const size_t OFF_INST  = 0;                          // [4096][768] bf16
  const size_t OFF_SLOTS = OFF_INST  + 6291456;        // [32768][256] bf16
  const size_t OFF_WFT   = OFF_SLOTS + 16777216;       // [1536][768] bf16
  const size_t OFF_BFCAT = OFF_WFT   + 2359296;        // [1536] f32
  const size_t OFF_KC    = OFF_BFCAT + 6144;           // [512][768] bf16
  const size_t OFF_KP    = OFF_KC    + 786432;
  const size_t OFF_VCT   = OFF_KP    + 786432;         // [768][512] bf16
  const size_t OFF_VPT   = OFF_VCT   + 786432;
  const size_t OFF_W1TP  = OFF_VPT   + 786432;         // [256][1024] bf16
  const size_t OFF_W1TU  = OFF_W1TP  + 524288;
  const size_t OFF_W2TP  = OFF_W1TU  + 524288;         // [256][256] bf16
  const size_t OFF_W2TU  = OFF_W2TP  + 131072;
  const size_t OFF_CP    = OFF_W2TU  + 131072;         // [2][4096][768] bf16
  const size_t OFF_T     = OFF_CP    + 12582912;       // [2][4096][256] f32
  const size_t OFF_H     = OFF_T     + 8388608;        // [2][32768][256] bf16
  const size_t OFF_B     = OFF_H     + 33554432;       // transient region (67MB)
  // region B sub-layout (time-disjoint uses):
  const size_t OFF_SC    = OFF_B;                      // scores [2][4096][512] f32
  const size_t OFF_P     = OFF_B + 16777216;           // P [2][4096][512] bf16
  const size_t OFF_Q     = OFF_B + 25165824;           // Q [4096][1536] bf16
  const size_t OFF_HRAW  = OFF_B;                      // [2][32768][256] f32 (after P dead)
  const size_t OFF_G     = OFF_B;                      // [2][32768][256] f32 (after hraw dead)

  u16*   instb = (u16*)(ws + OFF_INST);
  u16*   slotb = (u16*)(ws + OFF_SLOTS);
  u16*   WfT   = (u16*)(ws + OFF_WFT);
  float* bfcat = (float*)(ws + OFF_BFCAT);
  u16*   Kcb   = (u16*)(ws + OFF_KC);
  u16*   Kpb   = (u16*)(ws + OFF_KP);
  u16*   VcT   = (u16*)(ws + OFF_VCT);
  u16*   VpT   = (u16*)(ws + OFF_VPT);
  u16*   W1Tp  = (u16*)(ws + OFF_W1TP);
  u16*   W1Tu  = (u16*)(ws + OFF_W1TU);
  u16*   W2Tp  = (u16*)(ws + OFF_W2TP);
  u16*   W2Tu  = (u16*)(ws + OFF_W2TU);
  u16*   cp0   = (u16*)(ws + OFF_CP);
  u16*   cp1   = cp0 + (size_t)BB * PP;
  float* t0    = (float*)(ws + OFF_T);
  float* t1    = t0 + (size_t)BB * SLOT;
  u16*   H0    = (u16*)(ws + OFF_H);
  u16*   H1    = H0 + (size_t)BKROWS * SLOT;
  float* sc    = (float*)(ws + OFF_SC);
  u16*   Pb    = (u16*)(ws + OFF_P);
  u16*   Qb    = (u16*)(ws + OFF_Q);
  float* hraw  = (float*)(ws + OFF_HRAW);
  float* g0    = (float*)(ws + OFF_G);
  float* g1    = g0 + (size_t)BKROWS * SLOT;

  // ---- prep: converts + transposes ----
  cvt_bf16<<<dim3(3072), 256, 0, stream>>>(inst, instb, BB * PP / 4);
  cvt_bf16<<<dim3(8192), 256, 0, stream>>>(slots, slotb, BKROWS * SLOT / 4);
  cvt_bf16<<<dim3(384),  256, 0, stream>>>(Kc, Kcb, NC * PP / 4);
  cvt_bf16<<<dim3(384),  256, 0, stream>>>(Kp, Kpb, NC * PP / 4);
  concat_bias<<<dim3(3), 256, 0, stream>>>(bfc, bfp, bfcat, PP);
  transpose_cvt<<<dim3(24, 24), 256, 0, stream>>>(Wfc, WfT,            PP, PP);
  transpose_cvt<<<dim3(24, 24), 256, 0, stream>>>(Wfp, WfT + PP * PP,  PP, PP);
  transpose_cvt<<<dim3(24, 16), 256, 0, stream>>>(Vc,  VcT,  NC, PP);
  transpose_cvt<<<dim3(24, 16), 256, 0, stream>>>(Vp,  VpT,  NC, PP);
  transpose_cvt<<<dim3(8, 32),  256, 0, stream>>>(pW1, W1Tp, SLOT + PP, HID);
  transpose_cvt<<<dim3(8, 32),  256, 0, stream>>>(uW1, W1Tu, SLOT + PP, HID);
  transpose_cvt<<<dim3(8, 8),   256, 0, stream>>>(pW2, W2Tp, HID, SLOT);
  transpose_cvt<<<dim3(8, 8),   256, 0, stream>>>(uW2, W2Tu, HID, SLOT);

  // ---- Q = inst @ [Wfc|Wfp] + [bfc|bfp]  -> bf16 [4096][1536] ----
  gemm_bt<1><<<dim3(32, 12, 1), 256, 0, stream>>>(
      instb, instb, PP, WfT, WfT, PP, bfcat, bfcat, nullptr, nullptr,
      Qb, Qb, 1536, PP);

  // ---- scores = Q[,c|p] @ K{c,p}^T  -> f32 [2][4096][512] ----
  gemm_bt<0><<<dim3(32, 4, 2), 256, 0, stream>>>(
      Qb, Qb + PP, 1536, Kcb, Kpb, PP, nullptr, nullptr, nullptr, nullptr,
      sc, sc + (size_t)BB * NC, NC, PP);

  // ---- softmax (alpha folded) -> P bf16 [2][4096][512] ----
  softmax_rows<<<dim3(2048), 256, 0, stream>>>(sc, Pb);

  // ---- c/p = P @ V  -> bf16 [2][4096][768] ----
  gemm_bt<2><<<dim3(32, 6, 2), 256, 0, stream>>>(
      Pb, Pb + (size_t)BB * NC, NC, VcT, VpT, NC, nullptr, nullptr,
      nullptr, nullptr, cp0, cp1, PP, NC);

  // ---- t = c @ W1[256:] + b1 -> f32 [2][4096][256] ----
  gemm_bt<3><<<dim3(32, 2, 2), 256, 0, stream>>>(
      cp0, cp1, PP, W1Tp + 256, W1Tu + 256, SLOT + PP, pb1, ub1,
      nullptr, nullptr, t0, t1, SLOT, PP);

  // ---- hraw = slots @ W1[:256] + t[b]  -> f32 [2][32768][256] ----
  gemm_bt<4><<<dim3(256, 2, 2), 256, 0, stream>>>(
      slotb, slotb, SLOT, W1Tp, W1Tu, SLOT + PP, nullptr, nullptr, t0, t1,
      hraw, hraw + (size_t)BKROWS * SLOT, SLOT, SLOT);

  // ---- H = bf16(relu(LN(hraw)*g+bt)) ----
  ln_relu<<<dim3(8192, 1, 2), 256, 0, stream>>>(hraw, pg, ug, pbt, ubt, H0);

  // ---- gates = H @ W2 + b2 -> f32 [2][32768][256] ----
  gemm_bt<3><<<dim3(256, 2, 2), 256, 0, stream>>>(
      H0, H1, SLOT, W2Tp, W2Tu, SLOT, pb2, ub2, nullptr, nullptr,
      g0, g1, SLOT, SLOT);

  // ---- out = slots + gp * gu ----
  combine<<<dim3(8192), 256, 0, stream>>>(slots, g0, g1, out);

  (void)in_sizes; (void)n_in; (void)out_size; (void)ws_size;
}

// Round 3
// 172.029 us; speedup vs baseline: 1.1451x; 1.1451x over previous
//
#include <hip/hip_runtime.h>
#include <stdint.h>

#define BB    4096
#define KS    8
#define PP    768
#define SLOT  256
#define HID   256
#define NC    512
#define BKROWS (BB*KS)          // 32768
typedef unsigned short u16;
typedef short bf16x8 __attribute__((ext_vector_type(8)));
typedef float f32x4  __attribute__((ext_vector_type(4)));

__device__ __forceinline__ u16 f2bf(float x) {
  union { float f; uint32_t u; } v; v.f = x;
  return (u16)((v.u + 0x7FFFu + ((v.u >> 16) & 1u)) >> 16);
}

__device__ __forceinline__ void gload_lds16(u16* ldst, const u16* gsrc) {
  __builtin_amdgcn_global_load_lds(
      (const __attribute__((address_space(1))) void*)gsrc,
      (__attribute__((address_space(3))) void*)ldst, 16, 0, 0);
}

// ---------------------------------------------------------------------------
// Generic GEMM: C[M,N] = A_bf16[M,K] @ Bt_bf16[N,K]^T (+ epilogue)  [verified R1]
// BM=BN=128, BK=64, 4 waves. EPI: 0=f32, 2=bf16, 3=+bias f32
// ---------------------------------------------------------------------------
template<int EPI>
__global__ __launch_bounds__(256) void gemm_bt(
    const u16* __restrict__ A0, const u16* __restrict__ A1, int lda,
    const u16* __restrict__ B0, const u16* __restrict__ B1, int ldb,
    const float* __restrict__ bias0, const float* __restrict__ bias1,
    void* __restrict__ out0, void* __restrict__ out1, int ldo,
    int K)
{
  const int z = blockIdx.z;
  const u16*   A    = z ? A1 : A0;
  const u16*   B    = z ? B1 : B0;
  const float* bias = z ? bias1 : bias0;
  void*        out  = z ? out1 : out0;

  __shared__ u16 lsA[128 * 64];
  __shared__ u16 lsB[128 * 64];

  const int tid  = threadIdx.x;
  const int w    = tid >> 6;
  const int lane = tid & 63;
  const int wm   = w >> 1, wn = w & 1;
  const int rl   = lane >> 4, cl = lane & 15;
  const int blockRow = blockIdx.x * 128;
  const int blockCol = blockIdx.y * 128;

  f32x4 acc[4][4];
  const f32x4 zero = {0.f, 0.f, 0.f, 0.f};
#pragma unroll
  for (int i = 0; i < 4; ++i)
#pragma unroll
    for (int j = 0; j < 4; ++j) acc[i][j] = zero;

  const u16* Ablk = A + (size_t)blockRow * lda;
  const u16* Bblk = B + (size_t)blockCol * ldb;

  for (int k0 = 0; k0 < K; k0 += 64) {
#pragma unroll
    for (int i = 0; i < 4; ++i) {
      int seg   = i * 4 + w;
      int off16 = seg * 64 + lane;
      int row   = off16 >> 3;
      int chunk = (off16 & 7) ^ (row & 7);
      gload_lds16(lsA + seg * 512, Ablk + (size_t)row * lda + k0 + chunk * 8);
      gload_lds16(lsB + seg * 512, Bblk + (size_t)row * ldb + k0 + chunk * 8);
    }
    __syncthreads();

#pragma unroll
    for (int ks = 0; ks < 2; ++ks) {
      bf16x8 aF[4], bF[4];
#pragma unroll
      for (int f = 0; f < 4; ++f) {
        int r  = wm * 64 + f * 16 + cl;
        int ca = ((ks * 4 + rl) ^ (r & 7)) * 8;
        aF[f] = *(const bf16x8*)(lsA + r * 64 + ca);
        int rn = wn * 64 + f * 16 + cl;
        int cb = ((ks * 4 + rl) ^ (rn & 7)) * 8;
        bF[f] = *(const bf16x8*)(lsB + rn * 64 + cb);
      }
#pragma unroll
      for (int fm = 0; fm < 4; ++fm)
#pragma unroll
        for (int fn = 0; fn < 4; ++fn)
          acc[fm][fn] = __builtin_amdgcn_mfma_f32_16x16x32_bf16(
              aF[fm], bF[fn], acc[fm][fn], 0, 0, 0);
    }
    __syncthreads();
  }

#pragma unroll
  for (int fm = 0; fm < 4; ++fm) {
#pragma unroll
    for (int fn = 0; fn < 4; ++fn) {
      f32x4 v = acc[fm][fn];
#pragma unroll
      for (int r = 0; r < 4; ++r) {
        int grow = blockRow + wm * 64 + fm * 16 + rl * 4 + r;
        int gcol = blockCol + wn * 64 + fn * 16 + cl;
        float x = v[r];
        if constexpr (EPI == 0) {
          ((float*)out)[(size_t)grow * ldo + gcol] = x;
        } else if constexpr (EPI == 2) {
          ((u16*)out)[(size_t)grow * ldo + gcol] = f2bf(x);
        } else if constexpr (EPI == 3) {
          x += bias[gcol];
          ((float*)out)[(size_t)grow * ldo + gcol] = x;
        }
      }
    }
  }
}

// ---------------------------------------------------------------------------
// prep kernels
// ---------------------------------------------------------------------------
__global__ __launch_bounds__(256) void cvt_bf16(const float* __restrict__ in,
                                                u16* __restrict__ outp, int n4) {
  int i = blockIdx.x * 256 + threadIdx.x;
  if (i < n4) {
    float4 v = ((const float4*)in)[i];
    ushort4 o;
    o.x = f2bf(v.x); o.y = f2bf(v.y); o.z = f2bf(v.z); o.w = f2bf(v.w);
    ((ushort4*)outp)[i] = o;
  }
}

__global__ __launch_bounds__(256) void transpose_cvt(const float* __restrict__ in,
                                                     u16* __restrict__ outp,
                                                     int R, int C) {
  __shared__ float tile[32][33];
  int tc = blockIdx.x * 32, tr = blockIdx.y * 32;
  int lx = threadIdx.x & 31, ly = threadIdx.x >> 5;
#pragma unroll
  for (int i = 0; i < 32; i += 8)
    tile[ly + i][lx] = in[(size_t)(tr + ly + i) * C + tc + lx];
  __syncthreads();
#pragma unroll
  for (int i = 0; i < 32; i += 8)
    outp[(size_t)(tc + ly + i) * R + tr + lx] = f2bf(tile[lx][ly + i]);
}

// sb[row] = dot(K[n,:], bf)  rows: [2][512]
__global__ __launch_bounds__(256) void gemv_sb(const float* __restrict__ K0,
                                               const float* __restrict__ K1,
                                               const float* __restrict__ b0,
                                               const float* __restrict__ b1,
                                               float* __restrict__ sb) {
  int w = threadIdx.x >> 6, lane = threadIdx.x & 63;
  int row = blockIdx.x * 4 + w;
  int br = row >> 9, n = row & 511;
  const float* Kr = (br ? K1 : K0) + (size_t)n * PP;
  const float* bf = br ? b1 : b0;
  float s = 0.f;
#pragma unroll
  for (int j = 0; j < 12; ++j) s += Kr[lane + j * 64] * bf[lane + j * 64];
#pragma unroll
  for (int o = 32; o; o >>= 1) s += __shfl_xor(s, o);
  if (!lane) sb[row] = s;
}

// ---------------------------------------------------------------------------
// softmax over rows of 512 with broadcast bias sb[n]; alpha folded
// ---------------------------------------------------------------------------
__global__ __launch_bounds__(256) void softmax_rows(const float* __restrict__ S,
                                                    const float* __restrict__ sb,
                                                    u16* __restrict__ Pp) {
  int w = threadIdx.x >> 6, lane = threadIdx.x & 63;
  size_t row = (size_t)blockIdx.x * 4 + w;
  const float* src = S + row * 512 + lane * 8;
  const float* sbr = sb + ((row >> 12) << 9) + lane * 8;
  float4 v0 = *(const float4*)src;
  float4 v1 = *(const float4*)(src + 4);
  float4 s0 = *(const float4*)sbr;
  float4 s1 = *(const float4*)(sbr + 4);
  float vv[8] = {v0.x + s0.x, v0.y + s0.y, v0.z + s0.z, v0.w + s0.w,
                 v1.x + s1.x, v1.y + s1.y, v1.z + s1.z, v1.w + s1.w};
  float m = vv[0];
#pragma unroll
  for (int j = 1; j < 8; ++j) m = fmaxf(m, vv[j]);
#pragma unroll
  for (int o = 32; o; o >>= 1) m = fmaxf(m, __shfl_xor(m, o));
  const float alpha = 0.03608439182435161f;   // 1/sqrt(768)
  float e[8], s = 0.f;
#pragma unroll
  for (int j = 0; j < 8; ++j) { e[j] = __expf((vv[j] - m) * alpha); s += e[j]; }
#pragma unroll
  for (int o = 32; o; o >>= 1) s += __shfl_xor(s, o);
  float inv = 1.f / s;
  union { u16 u[8]; uint4 q; } ou;
#pragma unroll
  for (int j = 0; j < 8; ++j) ou.u[j] = f2bf(e[j] * inv);
  *(uint4*)(Pp + row * 512 + lane * 8) = ou.q;
}

// ---------------------------------------------------------------------------
// FUSED back half: per block = 64 slot-rows x 256 cols, both branches.
//   acc = slots@W1[:256] + t ; LN*g+bt ; ReLU -> H(LDS bf16, swizzled)
//   gate = H@W2 + b2 ; out = slots + gp*gu
// 4 waves; wave wn owns cols [wn*64, wn*64+64); rows all 64 (fm=0..3).
// ---------------------------------------------------------------------------
__global__ __launch_bounds__(256, 2) void fused_update(
    const float* __restrict__ slots,      // [32768][256] f32
    const float* __restrict__ t0, const float* __restrict__ t1,  // [4096][256] f32 (b1 included)
    const u16* __restrict__ W1Tp, const u16* __restrict__ W1Tu,  // [256][1024] bf16 (k<256 used)
    const u16* __restrict__ W2Tp, const u16* __restrict__ W2Tu,  // [256][256] bf16
    const float* __restrict__ pg, const float* __restrict__ pbt,
    const float* __restrict__ ug, const float* __restrict__ ubt,
    const float* __restrict__ pb2, const float* __restrict__ ub2,
    float* __restrict__ outp)
{
  __shared__ u16 lsA[64 * 256];
  __shared__ u16 lsB[256 * 64];
  __shared__ float lstat[2][64][8];   // [br][row][0..3]=sum(wn), [4..7]=sumsq(wn)

  const int tid = threadIdx.x, w = tid >> 6, lane = tid & 63;
  const int wn = w;
  const int rl = lane >> 4, cl = lane & 15;
  const int blockRow = blockIdx.x * 64;

  // --- stage A: slots f32 -> bf16, swizzled (chunk ^= row&7 on 16B chunks)
#pragma unroll
  for (int it = 0; it < 16; ++it) {
    int L = it * 256 + tid;          // f32x4 index in [0,4096)
    int row = L >> 6, qc = L & 63;
    float4 v = *(const float4*)(slots + (size_t)(blockRow + row) * 256 + qc * 4);
    ushort4 b; b.x = f2bf(v.x); b.y = f2bf(v.y); b.z = f2bf(v.z); b.w = f2bf(v.w);
    int chunk = qc >> 1, half = qc & 1;
    *(ushort4*)(lsA + row * 256 + (((chunk ^ (row & 7)) << 3) + half * 4)) = b;
  }

  f32x4 accP[4][4], accU[4][4];
  const f32x4 zero = {0.f, 0.f, 0.f, 0.f};
#pragma unroll
  for (int i = 0; i < 4; ++i)
#pragma unroll
    for (int j = 0; j < 4; ++j) { accP[i][j] = zero; accU[i][j] = zero; }

  // --- GEMM1: K=256, BK=32, both branches share aF
  for (int step = 0; step < 8; ++step) {
#pragma unroll
    for (int i = 0; i < 8; ++i) {
      int seg = i * 4 + w;
      int off16 = seg * 64 + lane;           // [0,2048)
      const u16* Wsrc = (off16 < 1024) ? W1Tp : W1Tu;
      int bo = off16 & 1023;
      int n = bo >> 2, chunk = bo & 3;
      gload_lds16(lsB + seg * 512,
                  Wsrc + (size_t)n * 1024 + step * 32 + ((chunk ^ (n & 3)) << 3));
    }
    __syncthreads();
    bf16x8 aF[4], bP[4], bU[4];
#pragma unroll
    for (int f = 0; f < 4; ++f) {
      int row = f * 16 + cl;
      aF[f] = *(const bf16x8*)(lsA + row * 256 + (((step * 4 + rl) ^ (row & 7)) << 3));
      int n = wn * 64 + f * 16 + cl;                     // FIX: wave col offset
      bP[f] = *(const bf16x8*)(lsB + n * 32 + ((rl ^ (n & 3)) << 3));
      bU[f] = *(const bf16x8*)(lsB + 8192 + n * 32 + ((rl ^ (n & 3)) << 3));
    }
#pragma unroll
    for (int fm = 0; fm < 4; ++fm)
#pragma unroll
      for (int fn = 0; fn < 4; ++fn) {
        accP[fm][fn] = __builtin_amdgcn_mfma_f32_16x16x32_bf16(aF[fm], bP[fn], accP[fm][fn], 0, 0, 0);
        accU[fm][fn] = __builtin_amdgcn_mfma_f32_16x16x32_bf16(aF[fm], bU[fn], accU[fm][fn], 0, 0, 0);
      }
    __syncthreads();
  }

  // --- t add (b1 already folded into t by the t-GEMM)
#pragma unroll
  for (int fm = 0; fm < 4; ++fm) {
    size_t tr = (size_t)((blockRow >> 3) + fm * 2 + (rl >> 1)) * 256;
#pragma unroll
    for (int fn = 0; fn < 4; ++fn) {
      int col = wn * 64 + fn * 16 + cl;
      float tp = t0[tr + col], tu = t1[tr + col];
#pragma unroll
      for (int r = 0; r < 4; ++r) { accP[fm][fn][r] += tp; accU[fm][fn][r] += tu; }
    }
  }

  // --- LN stats: per-lane partials over fn, butterfly over cl, LDS over wn
#pragma unroll
  for (int fm = 0; fm < 4; ++fm) {
    f32x4 s = accP[fm][0] + accP[fm][1] + accP[fm][2] + accP[fm][3];
    f32x4 q = accP[fm][0] * accP[fm][0] + accP[fm][1] * accP[fm][1]
            + accP[fm][2] * accP[fm][2] + accP[fm][3] * accP[fm][3];
    f32x4 su = accU[fm][0] + accU[fm][1] + accU[fm][2] + accU[fm][3];
    f32x4 qu = accU[fm][0] * accU[fm][0] + accU[fm][1] * accU[fm][1]
             + accU[fm][2] * accU[fm][2] + accU[fm][3] * accU[fm][3];
#pragma unroll
    for (int o = 1; o < 16; o <<= 1) {
#pragma unroll
      for (int r = 0; r < 4; ++r) {
        s[r]  += __shfl_xor(s[r],  o);
        q[r]  += __shfl_xor(q[r],  o);
        su[r] += __shfl_xor(su[r], o);
        qu[r] += __shfl_xor(qu[r], o);
      }
    }
    if (cl == 0) {
#pragma unroll
      for (int r = 0; r < 4; ++r) {
        int row = fm * 16 + rl * 4 + r;
        lstat[0][row][wn]     = s[r];
        lstat[0][row][4 + wn] = q[r];
        lstat[1][row][wn]     = su[r];
        lstat[1][row][4 + wn] = qu[r];
      }
    }
  }
  __syncthreads();   // stats ready; all lsA reads of GEMM1 done

  float g_r[2][4], bt_r[2][4];
#pragma unroll
  for (int fn = 0; fn < 4; ++fn) {
    int col = wn * 64 + fn * 16 + cl;
    g_r[0][fn] = pg[col]; g_r[1][fn] = ug[col];
    bt_r[0][fn] = pbt[col]; bt_r[1][fn] = ubt[col];
  }

  // --- normalize U -> write Hu into lsA (swizzled);  normalize P -> packed regs
  uint32_t hp_pk[4][4][2];
#pragma unroll
  for (int fm = 0; fm < 4; ++fm) {
    float mean0[4], rstd0[4], mean1[4], rstd1[4];
#pragma unroll
    for (int r = 0; r < 4; ++r) {
      int row = fm * 16 + rl * 4 + r;
      f32x4 sv = *(const f32x4*)&lstat[1][row][0];
      f32x4 qv = *(const f32x4*)&lstat[1][row][4];
      float ss = sv[0] + sv[1] + sv[2] + sv[3];
      float qq = qv[0] + qv[1] + qv[2] + qv[3];
      float mu = ss * (1.f / 256.f);
      mean1[r] = mu; rstd1[r] = rsqrtf(qq * (1.f / 256.f) - mu * mu + 1e-5f);
      sv = *(const f32x4*)&lstat[0][row][0];
      qv = *(const f32x4*)&lstat[0][row][4];
      ss = sv[0] + sv[1] + sv[2] + sv[3];
      qq = qv[0] + qv[1] + qv[2] + qv[3];
      mu = ss * (1.f / 256.f);
      mean0[r] = mu; rstd0[r] = rsqrtf(qq * (1.f / 256.f) - mu * mu + 1e-5f);
    }
#pragma unroll
    for (int fn = 0; fn < 4; ++fn) {
      int col = wn * 64 + fn * 16 + cl;
      u16 hb[4];
#pragma unroll
      for (int r = 0; r < 4; ++r) {
        float h = fmaxf((accU[fm][fn][r] - mean1[r]) * rstd1[r] * g_r[1][fn] + bt_r[1][fn], 0.f);
        int row = fm * 16 + rl * 4 + r;
        lsA[row * 256 + (((col >> 3) ^ (row & 7)) << 3) + (col & 7)] = f2bf(h);
        float hp = fmaxf((accP[fm][fn][r] - mean0[r]) * rstd0[r] * g_r[0][fn] + bt_r[0][fn], 0.f);
        hb[r] = f2bf(hp);
      }
      hp_pk[fm][fn][0] = (uint32_t)hb[0] | ((uint32_t)hb[1] << 16);
      hp_pk[fm][fn][1] = (uint32_t)hb[2] | ((uint32_t)hb[3] << 16);
    }
  }
  __syncthreads();   // Hu visible

  f32x4 gU[4][4], gP[4][4];
#pragma unroll
  for (int i = 0; i < 4; ++i)
#pragma unroll
    for (int j = 0; j < 4; ++j) { gU[i][j] = zero; gP[i][j] = zero; }

#define GEMM2(W2T, gacc)                                                        \
  for (int step = 0; step < 4; ++step) {                                        \
    _Pragma("unroll")                                                           \
    for (int i = 0; i < 8; ++i) {                                               \
      int seg = i * 4 + w;                                                      \
      int off16 = seg * 64 + lane;                                              \
      int n = off16 >> 3, chunk = off16 & 7;                                    \
      gload_lds16(lsB + seg * 512,                                              \
                  W2T + (size_t)n * 256 + step * 64 + ((chunk ^ (n & 7)) << 3));\
    }                                                                           \
    __syncthreads();                                                            \
    _Pragma("unroll")                                                           \
    for (int ks = 0; ks < 2; ++ks) {                                            \
      bf16x8 aF[4], bF[4];                                                      \
      _Pragma("unroll")                                                         \
      for (int f = 0; f < 4; ++f) {                                             \
        int row = f * 16 + cl;                                                  \
        int ch = step * 8 + ks * 4 + rl;                                        \
        aF[f] = *(const bf16x8*)(lsA + row * 256 + ((ch ^ (row & 7)) << 3));    \
        int n = wn * 64 + f * 16 + cl;              /* FIX: wave col offset */  \
        bF[f] = *(const bf16x8*)(lsB + n * 64 + (((ks * 4 + rl) ^ (n & 7)) << 3)); \
      }                                                                         \
      _Pragma("unroll")                                                         \
      for (int fm = 0; fm < 4; ++fm)                                            \
        _Pragma("unroll")                                                       \
        for (int fn = 0; fn < 4; ++fn)                                          \
          gacc[fm][fn] = __builtin_amdgcn_mfma_f32_16x16x32_bf16(               \
              aF[fm], bF[fn], gacc[fm][fn], 0, 0, 0);                           \
    }                                                                           \
    __syncthreads();                                                            \
  }

  GEMM2(W2Tu, gU)

  // --- write Hp into lsA, then GEMM2 for P branch
#pragma unroll
  for (int fm = 0; fm < 4; ++fm)
#pragma unroll
    for (int fn = 0; fn < 4; ++fn) {
      int col = wn * 64 + fn * 16 + cl;
#pragma unroll
      for (int r = 0; r < 4; ++r) {
        int row = fm * 16 + rl * 4 + r;
        u16 hb = (u16)(hp_pk[fm][fn][r >> 1] >> ((r & 1) * 16));
        lsA[row * 256 + (((col >> 3) ^ (row & 7)) << 3) + (col & 7)] = hb;
      }
    }
  __syncthreads();

  GEMM2(W2Tp, gP)
#undef GEMM2

  // --- epilogue: out = slots + gp*gu
  float b2p[4], b2u[4];
#pragma unroll
  for (int fn = 0; fn < 4; ++fn) {
    int col = wn * 64 + fn * 16 + cl;
    b2p[fn] = pb2[col]; b2u[fn] = ub2[col];
  }
#pragma unroll
  for (int fm = 0; fm < 4; ++fm)
#pragma unroll
    for (int fn = 0; fn < 4; ++fn) {
      int col = wn * 64 + fn * 16 + cl;
#pragma unroll
      for (int r = 0; r < 4; ++r) {
        int row = blockRow + fm * 16 + rl * 4 + r;
        size_t idx = (size_t)row * 256 + col;
        float gp = gP[fm][fn][r] + b2p[fn];
        float gu = gU[fm][fn][r] + b2u[fn];
        outp[idx] = slots[idx] + gp * gu;
      }
    }
}

// ---------------------------------------------------------------------------
// host launcher
// ---------------------------------------------------------------------------
extern "C" void kernel_launch(void* const* d_in, const int* in_sizes, int n_in,
                              void* d_out, int out_size, void* d_ws, size_t ws_size,
                              hipStream_t stream) {
  const float* inst  = (const float*)d_in[0];
  const float* slots = (const float*)d_in[1];
  const float* Wfc   = (const float*)d_in[2];
  const float* bfc   = (const float*)d_in[3];
  const float* Wfp   = (const float*)d_in[4];
  const float* bfp   = (const float*)d_in[5];
  const float* Kc    = (const float*)d_in[6];
  const float* Vc    = (const float*)d_in[7];
  const float* Kp    = (const float*)d_in[8];
  const float* Vp    = (const float*)d_in[9];
  const float* pW1   = (const float*)d_in[10];
  const float* pb1   = (const float*)d_in[11];
  const float* pg    = (const float*)d_in[12];
  const float* pbt   = (const float*)d_in[13];
  const float* pW2   = (const float*)d_in[14];
  const float* pb2   = (const float*)d_in[15];
  const float* uW1   = (const float*)d_in[16];
  const float* ub1   = (const float*)d_in[17];
  const float* ug    = (const float*)d_in[18];
  const float* ubt   = (const float*)d_in[19];
  const float* uW2   = (const float*)d_in[20];
  const float* ub2   = (const float*)d_in[21];
  float* out = (float*)d_out;
  char*  ws  = (char*)d_ws;

  // ---- workspace layout (bytes) ----
  const size_t OFF_INST  = 0;                         // [4096][768] bf16
  const size_t OFF_KC    = OFF_INST  + 6291456;       // [512][768] bf16 x2
  const size_t OFF_KP    = OFF_KC    + 786432;
  const size_t OFF_WFCB  = OFF_KP    + 786432;        // [768][768] bf16 x2
  const size_t OFF_WFPB  = OFF_WFCB  + 1179648;
  const size_t OFF_VCB   = OFF_WFPB  + 1179648;       // [512][768] bf16 x2
  const size_t OFF_VPB   = OFF_VCB   + 786432;
  const size_t OFF_W1TP  = OFF_VPB   + 786432;        // [256][1024] bf16 x2
  const size_t OFF_W1TU  = OFF_W1TP  + 524288;
  const size_t OFF_W2TP  = OFF_W1TU  + 524288;        // [256][256] bf16 x2
  const size_t OFF_W2TU  = OFF_W2TP  + 131072;
  const size_t OFF_KW    = OFF_W2TU  + 131072;        // [2][512][768] bf16
  const size_t OFF_VW1   = OFF_KW    + 1572864;       // [2][256][512] bf16
  const size_t OFF_SB    = OFF_VW1   + 524288;        // [2][512] f32
  const size_t OFF_T     = OFF_SB    + 4096;          // [2][4096][256] f32
  const size_t OFF_SC    = OFF_T     + 8388608;       // [2][4096][512] f32
  const size_t OFF_P     = OFF_SC    + 16777216;      // [2][4096][512] bf16

  u16*   instb = (u16*)(ws + OFF_INST);
  u16*   Kcb   = (u16*)(ws + OFF_KC);
  u16*   Kpb   = (u16*)(ws + OFF_KP);
  u16*   Wfcb  = (u16*)(ws + OFF_WFCB);
  u16*   Wfpb  = (u16*)(ws + OFF_WFPB);
  u16*   Vcb   = (u16*)(ws + OFF_VCB);
  u16*   Vpb   = (u16*)(ws + OFF_VPB);
  u16*   W1Tp  = (u16*)(ws + OFF_W1TP);
  u16*   W1Tu  = (u16*)(ws + OFF_W1TU);
  u16*   W2Tp  = (u16*)(ws + OFF_W2TP);
  u16*   W2Tu  = (u16*)(ws + OFF_W2TU);
  u16*   KWc   = (u16*)(ws + OFF_KW);
  u16*   KWp   = KWc + (size_t)NC * PP;
  u16*   VW1p  = (u16*)(ws + OFF_VW1);
  u16*   VW1u  = VW1p + (size_t)SLOT * NC;
  float* sb    = (float*)(ws + OFF_SB);
  float* t0    = (float*)(ws + OFF_T);
  float* t1    = t0 + (size_t)BB * SLOT;
  float* sc    = (float*)(ws + OFF_SC);
  u16*   Pb    = (u16*)(ws + OFF_P);

  // ---- prep ----
  cvt_bf16<<<dim3(3072), 256, 0, stream>>>(inst, instb, BB * PP / 4);
  cvt_bf16<<<dim3(384),  256, 0, stream>>>(Kc, Kcb, NC * PP / 4);
  cvt_bf16<<<dim3(384),  256, 0, stream>>>(Kp, Kpb, NC * PP / 4);
  cvt_bf16<<<dim3(576),  256, 0, stream>>>(Wfc, Wfcb, PP * PP / 4);
  cvt_bf16<<<dim3(576),  256, 0, stream>>>(Wfp, Wfpb, PP * PP / 4);
  cvt_bf16<<<dim3(384),  256, 0, stream>>>(Vc, Vcb, NC * PP / 4);
  cvt_bf16<<<dim3(384),  256, 0, stream>>>(Vp, Vpb, NC * PP / 4);
  transpose_cvt<<<dim3(8, 32), 256, 0, stream>>>(pW1, W1Tp, SLOT + PP, HID);
  transpose_cvt<<<dim3(8, 32), 256, 0, stream>>>(uW1, W1Tu, SLOT + PP, HID);
  transpose_cvt<<<dim3(8, 8),  256, 0, stream>>>(pW2, W2Tp, HID, SLOT);
  transpose_cvt<<<dim3(8, 8),  256, 0, stream>>>(uW2, W2Tu, HID, SLOT);

  // ---- KW[n][j] = sum_i K[n][i] * Wf[j][i]   [2][512][768] bf16 ----
  gemm_bt<2><<<dim3(4, 6, 2), 256, 0, stream>>>(
      Kcb, Kpb, PP, Wfcb, Wfpb, PP, nullptr, nullptr,
      KWc, KWp, PP, PP);

  // ---- sb[br][n] = dot(K[n,:], bf)  (exact f32) ----
  gemv_sb<<<dim3(256), 256, 0, stream>>>(Kc, Kp, bfc, bfp, sb);

  // ---- VW1T[j][n] = sum_i W1[256+i][j] * V[n][i]   [2][256][512] bf16 ----
  gemm_bt<2><<<dim3(2, 4, 2), 256, 0, stream>>>(
      W1Tp + 256, W1Tu + 256, 1024, Vcb, Vpb, PP, nullptr, nullptr,
      VW1p, VW1u, NC, PP);

  // ---- scores = inst @ KW^T  -> f32 [2][4096][512] ----
  gemm_bt<0><<<dim3(32, 4, 2), 256, 0, stream>>>(
      instb, instb, PP, KWc, KWp, PP, nullptr, nullptr,
      sc, sc + (size_t)BB * NC, NC, PP);

  // ---- P = softmax((sc+sb)*alpha) -> bf16 ----
  softmax_rows<<<dim3(2048), 256, 0, stream>>>(sc, sb, Pb);

  // ---- t = P @ VW1 + b1 -> f32 [2][4096][256] ----
  gemm_bt<3><<<dim3(32, 2, 2), 256, 0, stream>>>(
      Pb, Pb + (size_t)BB * NC, NC, VW1p, VW1u, NC, pb1, ub1,
      t0, t1, SLOT, NC);

  // ---- fused back half ----
  fused_update<<<dim3(512), 256, 0, stream>>>(
      slots, t0, t1, W1Tp, W1Tu, W2Tp, W2Tu,
      pg, pbt, ug, ubt, pb2, ub2, out);

  (void)in_sizes; (void)n_in; (void)out_size; (void)ws_size;
}

// Round 4
// 131.585 us; speedup vs baseline: 1.4970x; 1.3074x over previous
//
#include <hip/hip_runtime.h>
#include <stdint.h>

#define BB    4096
#define KS    8
#define PP    768
#define SLOT  256
#define HID   256
#define NC    512
#define BKROWS (BB*KS)          // 32768
typedef unsigned short u16;
typedef short bf16x8 __attribute__((ext_vector_type(8)));
typedef float f32x4  __attribute__((ext_vector_type(4)));

__device__ __forceinline__ u16 f2bf(float x) {
  union { float f; uint32_t u; } v; v.f = x;
  return (u16)((v.u + 0x7FFFu + ((v.u >> 16) & 1u)) >> 16);
}

__device__ __forceinline__ void gload_lds16(u16* ldst, const u16* gsrc) {
  __builtin_amdgcn_global_load_lds(
      (const __attribute__((address_space(1))) void*)gsrc,
      (__attribute__((address_space(3))) void*)ldst, 16, 0, 0);
}

// ---------------------------------------------------------------------------
// Generic GEMM core: C[M,N] = A_bf16[M,K] @ Bt_bf16[N,K]^T (+ epilogue)
// BM=BN=128, BK=64, 4 waves. EPI: 0=f32, 2=bf16, 3=+bias f32  [verified R1/R3]
// ---------------------------------------------------------------------------
template<int EPI>
__device__ __forceinline__ void gemm_core(
    const u16* __restrict__ A, int lda,
    const u16* __restrict__ B, int ldb,
    const float* __restrict__ bias,
    void* __restrict__ out, int ldo, int K,
    int blockRow, int blockCol, u16* lsA, u16* lsB)
{
  const int tid  = threadIdx.x;
  const int w    = tid >> 6;
  const int lane = tid & 63;
  const int wm   = w >> 1, wn = w & 1;
  const int rl   = lane >> 4, cl = lane & 15;

  f32x4 acc[4][4];
  const f32x4 zero = {0.f, 0.f, 0.f, 0.f};
#pragma unroll
  for (int i = 0; i < 4; ++i)
#pragma unroll
    for (int j = 0; j < 4; ++j) acc[i][j] = zero;

  const u16* Ablk = A + (size_t)blockRow * lda;
  const u16* Bblk = B + (size_t)blockCol * ldb;

  for (int k0 = 0; k0 < K; k0 += 64) {
#pragma unroll
    for (int i = 0; i < 4; ++i) {
      int seg   = i * 4 + w;
      int off16 = seg * 64 + lane;
      int row   = off16 >> 3;
      int chunk = (off16 & 7) ^ (row & 7);
      gload_lds16(lsA + seg * 512, Ablk + (size_t)row * lda + k0 + chunk * 8);
      gload_lds16(lsB + seg * 512, Bblk + (size_t)row * ldb + k0 + chunk * 8);
    }
    __syncthreads();

#pragma unroll
    for (int ks = 0; ks < 2; ++ks) {
      bf16x8 aF[4], bF[4];
#pragma unroll
      for (int f = 0; f < 4; ++f) {
        int r  = wm * 64 + f * 16 + cl;
        int ca = ((ks * 4 + rl) ^ (r & 7)) * 8;
        aF[f] = *(const bf16x8*)(lsA + r * 64 + ca);
        int rn = wn * 64 + f * 16 + cl;
        int cb = ((ks * 4 + rl) ^ (rn & 7)) * 8;
        bF[f] = *(const bf16x8*)(lsB + rn * 64 + cb);
      }
#pragma unroll
      for (int fm = 0; fm < 4; ++fm)
#pragma unroll
        for (int fn = 0; fn < 4; ++fn)
          acc[fm][fn] = __builtin_amdgcn_mfma_f32_16x16x32_bf16(
              aF[fm], bF[fn], acc[fm][fn], 0, 0, 0);
    }
    __syncthreads();
  }

#pragma unroll
  for (int fm = 0; fm < 4; ++fm) {
#pragma unroll
    for (int fn = 0; fn < 4; ++fn) {
      f32x4 v = acc[fm][fn];
#pragma unroll
      for (int r = 0; r < 4; ++r) {
        int grow = blockRow + wm * 64 + fm * 16 + rl * 4 + r;
        int gcol = blockCol + wn * 64 + fn * 16 + cl;
        float x = v[r];
        if constexpr (EPI == 0) {
          ((float*)out)[(size_t)grow * ldo + gcol] = x;
        } else if constexpr (EPI == 2) {
          ((u16*)out)[(size_t)grow * ldo + gcol] = f2bf(x);
        } else if constexpr (EPI == 3) {
          x += bias[gcol];
          ((float*)out)[(size_t)grow * ldo + gcol] = x;
        }
      }
    }
  }
}

// ---------------------------------------------------------------------------
// prep_all: one dispatch for every cvt / transpose / frag-pack / sb gemv.
// Block ranges:
//   [0,3072)    cvt inst      [3072,3456) cvt Kc    [3456,3840) cvt Kp
//   [3840,4416) cvt Wfc       [4416,4992) cvt Wfp
//   [4992,5376) cvt Vc        [5376,5760) cvt Vp
//   [5760,6016) transpose pW1 -> W1Tp   [6016,6272) transpose uW1 -> W1Tu
//   [6272,6304) pack W1pk     [6304,6336) pack W2pk
//   [6336,6592) gemv sb
// ---------------------------------------------------------------------------
__device__ __forceinline__ void cvt_seg(const float* __restrict__ in,
                                        u16* __restrict__ outp, int b, int n4) {
  int i = b * 256 + threadIdx.x;
  if (i < n4) {
    float4 v = ((const float4*)in)[i];
    ushort4 o;
    o.x = f2bf(v.x); o.y = f2bf(v.y); o.z = f2bf(v.z); o.w = f2bf(v.w);
    ((ushort4*)outp)[i] = o;
  }
}

// frag-pack: dst[((br*16+ng)*8+step)*64 + lane][j] = src[step*32 + rl*8 + j][ng*16 + cl]
__device__ __forceinline__ void pack_seg(const float* __restrict__ s0,
                                         const float* __restrict__ s1,
                                         u16* __restrict__ dst, int b) {
  int br = b >> 4, ng = b & 15;
  const float* src = br ? s1 : s0;
  int w = threadIdx.x >> 6, lane = threadIdx.x & 63;
  int rl = lane >> 4, cl = lane & 15;
#pragma unroll
  for (int s = 0; s < 2; ++s) {
    int step = w * 2 + s;
    union { u16 u[8]; uint4 q; } o;
#pragma unroll
    for (int j = 0; j < 8; ++j)
      o.u[j] = f2bf(src[(size_t)(step * 32 + rl * 8 + j) * 256 + ng * 16 + cl]);
    *(uint4*)(dst + (size_t)(((br * 16 + ng) * 8 + step) * 64 + lane) * 8) = o.q;
  }
}

__global__ __launch_bounds__(256) void prep_all(
    const float* __restrict__ inst, const float* __restrict__ Kc,
    const float* __restrict__ Kp, const float* __restrict__ Wfc,
    const float* __restrict__ Wfp, const float* __restrict__ Vc,
    const float* __restrict__ Vp, const float* __restrict__ pW1,
    const float* __restrict__ uW1, const float* __restrict__ pW2,
    const float* __restrict__ uW2, const float* __restrict__ bfc,
    const float* __restrict__ bfp,
    u16* instb, u16* Kcb, u16* Kpb, u16* Wfcb, u16* Wfpb, u16* Vcb, u16* Vpb,
    u16* W1Tp, u16* W1Tu, u16* W1pk, u16* W2pk, float* sb)
{
  __shared__ float tile[32][33];
  int b = blockIdx.x;
  if (b < 3072)      { cvt_seg(inst, instb, b,        786432); return; }
  else if (b < 3456) { cvt_seg(Kc,   Kcb,   b - 3072,  98304); return; }
  else if (b < 3840) { cvt_seg(Kp,   Kpb,   b - 3456,  98304); return; }
  else if (b < 4416) { cvt_seg(Wfc,  Wfcb,  b - 3840, 147456); return; }
  else if (b < 4992) { cvt_seg(Wfp,  Wfpb,  b - 4416, 147456); return; }
  else if (b < 5376) { cvt_seg(Vc,   Vcb,   b - 4992,  98304); return; }
  else if (b < 5760) { cvt_seg(Vp,   Vpb,   b - 5376,  98304); return; }
  else if (b < 6272) {
    // transpose [1024][256] f32 -> [256][1024] bf16
    int bb = b - 5760;
    const float* in = (bb < 256) ? pW1 : uW1;
    u16* outp = (bb < 256) ? W1Tp : W1Tu;
    bb &= 255;
    int tc = (bb & 7) * 32, tr = (bb >> 3) * 32;
    int lx = threadIdx.x & 31, ly = threadIdx.x >> 5;
#pragma unroll
    for (int i = 0; i < 32; i += 8)
      tile[ly + i][lx] = in[(size_t)(tr + ly + i) * 256 + tc + lx];
    __syncthreads();
#pragma unroll
    for (int i = 0; i < 32; i += 8)
      outp[(size_t)(tc + ly + i) * 1024 + tr + lx] = f2bf(tile[lx][ly + i]);
    return;
  }
  else if (b < 6304) { pack_seg(pW1, uW1, W1pk, b - 6272); return; }
  else if (b < 6336) { pack_seg(pW2, uW2, W2pk, b - 6304); return; }
  else {
    // sb[row] = dot(K[n,:], bf)
    int w = threadIdx.x >> 6, lane = threadIdx.x & 63;
    int row = (b - 6336) * 4 + w;
    int br = row >> 9, n = row & 511;
    const float* Kr = (br ? Kp : Kc) + (size_t)n * PP;
    const float* bf = br ? bfp : bfc;
    float s = 0.f;
#pragma unroll
    for (int j = 0; j < 12; ++j) s += Kr[lane + j * 64] * bf[lane + j * 64];
#pragma unroll
    for (int o = 32; o; o >>= 1) s += __shfl_xor(s, o);
    if (!lane) sb[row] = s;
  }
}

// ---------------------------------------------------------------------------
// merged small GEMMs: blocks [0,48) = KW (M=512,N=768,K=768);
//                     blocks [48,64) = VW1 (M=256,N=512,K=768)
// ---------------------------------------------------------------------------
__global__ __launch_bounds__(256) void gemm_mixed(
    const u16* Kcb, const u16* Kpb, const u16* Wfcb, const u16* Wfpb,
    u16* KWc, u16* KWp,
    const u16* W1Tp, const u16* W1Tu, const u16* Vcb, const u16* Vpb,
    u16* VW1p, u16* VW1u)
{
  __shared__ u16 lsA[128 * 64];
  __shared__ u16 lsB[128 * 64];
  int b = blockIdx.x;
  if (b < 48) {
    int z = b / 24, r = b % 24;
    gemm_core<2>(z ? Kpb : Kcb, PP, z ? Wfpb : Wfcb, PP, nullptr,
                 z ? KWp : KWc, PP, PP, (r & 3) * 128, (r >> 2) * 128, lsA, lsB);
  } else {
    int c = b - 48, z = c / 8, r = c % 8;
    gemm_core<2>((z ? W1Tu : W1Tp) + 256, 1024, z ? Vpb : Vcb, PP, nullptr,
                 z ? VW1u : VW1p, NC, PP, (r & 1) * 128, (r >> 1) * 128, lsA, lsB);
  }
}

__global__ __launch_bounds__(256) void gemm_scores(
    const u16* instb, const u16* KWc, const u16* KWp, float* sc)
{
  __shared__ u16 lsA[128 * 64];
  __shared__ u16 lsB[128 * 64];
  int z = blockIdx.z;
  gemm_core<0>(instb, PP, z ? KWp : KWc, PP, nullptr,
               sc + (size_t)z * BB * NC, NC, PP,
               blockIdx.x * 128, blockIdx.y * 128, lsA, lsB);
}

__global__ __launch_bounds__(256) void gemm_t(
    const u16* Pb, const u16* VW1p, const u16* VW1u,
    const float* pb1, const float* ub1, float* t0, float* t1)
{
  __shared__ u16 lsA[128 * 64];
  __shared__ u16 lsB[128 * 64];
  int z = blockIdx.z;
  gemm_core<3>(Pb + (size_t)z * BB * NC, NC, z ? VW1u : VW1p, NC,
               z ? ub1 : pb1, z ? t1 : t0, SLOT, NC,
               blockIdx.x * 128, blockIdx.y * 128, lsA, lsB);
}

// ---------------------------------------------------------------------------
// softmax over rows of 512 with broadcast bias sb[n]; alpha folded
// ---------------------------------------------------------------------------
__global__ __launch_bounds__(256) void softmax_rows(const float* __restrict__ S,
                                                    const float* __restrict__ sb,
                                                    u16* __restrict__ Pp) {
  int w = threadIdx.x >> 6, lane = threadIdx.x & 63;
  size_t row = (size_t)blockIdx.x * 4 + w;
  const float* src = S + row * 512 + lane * 8;
  const float* sbr = sb + ((row >> 12) << 9) + lane * 8;
  float4 v0 = *(const float4*)src;
  float4 v1 = *(const float4*)(src + 4);
  float4 s0 = *(const float4*)sbr;
  float4 s1 = *(const float4*)(sbr + 4);
  float vv[8] = {v0.x + s0.x, v0.y + s0.y, v0.z + s0.z, v0.w + s0.w,
                 v1.x + s1.x, v1.y + s1.y, v1.z + s1.z, v1.w + s1.w};
  float m = vv[0];
#pragma unroll
  for (int j = 1; j < 8; ++j) m = fmaxf(m, vv[j]);
#pragma unroll
  for (int o = 32; o; o >>= 1) m = fmaxf(m, __shfl_xor(m, o));
  const float alpha = 0.03608439182435161f;   // 1/sqrt(768)
  float e[8], s = 0.f;
#pragma unroll
  for (int j = 0; j < 8; ++j) { e[j] = __expf((vv[j] - m) * alpha); s += e[j]; }
#pragma unroll
  for (int o = 32; o; o >>= 1) s += __shfl_xor(s, o);
  float inv = 1.f / s;
  union { u16 u[8]; uint4 q; } ou;
#pragma unroll
  for (int j = 0; j < 8; ++j) ou.u[j] = f2bf(e[j] * inv);
  *(uint4*)(Pp + row * 512 + lane * 8) = ou.q;
}

// ---------------------------------------------------------------------------
// FUSED back half, v2: no lsB — B-operands come straight from L2 via the
// fragment-packed W1pk/W2pk (one coalesced 16B load per lane per fragment).
// Only 5 barriers total. LDS 36 KB.
// ---------------------------------------------------------------------------
__global__ __launch_bounds__(256) void fused_update(
    const float* __restrict__ slots,      // [32768][256] f32
    const float* __restrict__ t0, const float* __restrict__ t1,
    const u16* __restrict__ W1pk, const u16* __restrict__ W2pk,
    const float* __restrict__ pg, const float* __restrict__ pbt,
    const float* __restrict__ ug, const float* __restrict__ ubt,
    const float* __restrict__ pb2, const float* __restrict__ ub2,
    float* __restrict__ outp)
{
  __shared__ u16 lsA[64 * 256];       // 32 KB: slots tile -> Hu -> Hp
  __shared__ float lstat[2][64][8];   //  4 KB

  const int tid = threadIdx.x, wn = tid >> 6, lane = tid & 63;
  const int rl = lane >> 4, cl = lane & 15;
  const int blockRow = blockIdx.x * 64;

  // --- stage slots f32 -> bf16, swizzled
#pragma unroll
  for (int it = 0; it < 16; ++it) {
    int L = it * 256 + tid;
    int row = L >> 6, qc = L & 63;
    float4 v = *(const float4*)(slots + (size_t)(blockRow + row) * 256 + qc * 4);
    ushort4 b; b.x = f2bf(v.x); b.y = f2bf(v.y); b.z = f2bf(v.z); b.w = f2bf(v.w);
    int chunk = qc >> 1, half = qc & 1;
    *(ushort4*)(lsA + row * 256 + (((chunk ^ (row & 7)) << 3) + half * 4)) = b;
  }
  __syncthreads();                                   // B1

  f32x4 accP[4][4], accU[4][4];
  const f32x4 zero = {0.f, 0.f, 0.f, 0.f};
#pragma unroll
  for (int i = 0; i < 4; ++i)
#pragma unroll
    for (int j = 0; j < 4; ++j) { accP[i][j] = zero; accU[i][j] = zero; }

  // --- GEMM1: K=256 (8 steps of 32), no barriers
#pragma unroll
  for (int step = 0; step < 8; ++step) {
    bf16x8 aF[4], bP[4], bU[4];
#pragma unroll
    for (int f = 0; f < 4; ++f) {
      int row = f * 16 + cl;
      aF[f] = *(const bf16x8*)(lsA + row * 256 + (((step * 4 + rl) ^ (row & 7)) << 3));
      int ng = wn * 4 + f;
      bP[f] = *(const bf16x8*)(W1pk + (size_t)((ng * 8 + step) * 64 + lane) * 8);
      bU[f] = *(const bf16x8*)(W1pk + (size_t)(((16 + ng) * 8 + step) * 64 + lane) * 8);
    }
#pragma unroll
    for (int fm = 0; fm < 4; ++fm)
#pragma unroll
      for (int fn = 0; fn < 4; ++fn) {
        accP[fm][fn] = __builtin_amdgcn_mfma_f32_16x16x32_bf16(aF[fm], bP[fn], accP[fm][fn], 0, 0, 0);
        accU[fm][fn] = __builtin_amdgcn_mfma_f32_16x16x32_bf16(aF[fm], bU[fn], accU[fm][fn], 0, 0, 0);
      }
  }

  // --- t add (b1 folded into t)
#pragma unroll
  for (int fm = 0; fm < 4; ++fm) {
    size_t tr = (size_t)((blockRow >> 3) + fm * 2 + (rl >> 1)) * 256;
#pragma unroll
    for (int fn = 0; fn < 4; ++fn) {
      int col = wn * 64 + fn * 16 + cl;
      float tp = t0[tr + col], tu = t1[tr + col];
#pragma unroll
      for (int r = 0; r < 4; ++r) { accP[fm][fn][r] += tp; accU[fm][fn][r] += tu; }
    }
  }

  // --- LN stats
#pragma unroll
  for (int fm = 0; fm < 4; ++fm) {
    f32x4 s = accP[fm][0] + accP[fm][1] + accP[fm][2] + accP[fm][3];
    f32x4 q = accP[fm][0] * accP[fm][0] + accP[fm][1] * accP[fm][1]
            + accP[fm][2] * accP[fm][2] + accP[fm][3] * accP[fm][3];
    f32x4 su = accU[fm][0] + accU[fm][1] + accU[fm][2] + accU[fm][3];
    f32x4 qu = accU[fm][0] * accU[fm][0] + accU[fm][1] * accU[fm][1]
             + accU[fm][2] * accU[fm][2] + accU[fm][3] * accU[fm][3];
#pragma unroll
    for (int o = 1; o < 16; o <<= 1) {
#pragma unroll
      for (int r = 0; r < 4; ++r) {
        s[r]  += __shfl_xor(s[r],  o);
        q[r]  += __shfl_xor(q[r],  o);
        su[r] += __shfl_xor(su[r], o);
        qu[r] += __shfl_xor(qu[r], o);
      }
    }
    if (cl == 0) {
#pragma unroll
      for (int r = 0; r < 4; ++r) {
        int row = fm * 16 + rl * 4 + r;
        lstat[0][row][wn]     = s[r];
        lstat[0][row][4 + wn] = q[r];
        lstat[1][row][wn]     = su[r];
        lstat[1][row][4 + wn] = qu[r];
      }
    }
  }
  __syncthreads();                                   // B2

  float g_r[2][4], bt_r[2][4];
#pragma unroll
  for (int fn = 0; fn < 4; ++fn) {
    int col = wn * 64 + fn * 16 + cl;
    g_r[0][fn] = pg[col]; g_r[1][fn] = ug[col];
    bt_r[0][fn] = pbt[col]; bt_r[1][fn] = ubt[col];
  }

  // --- normalize: Hu -> lsA (swizzled), Hp -> packed regs
  uint32_t hp_pk[4][4][2];
#pragma unroll
  for (int fm = 0; fm < 4; ++fm) {
    float mean0[4], rstd0[4], mean1[4], rstd1[4];
#pragma unroll
    for (int r = 0; r < 4; ++r) {
      int row = fm * 16 + rl * 4 + r;
      f32x4 sv = *(const f32x4*)&lstat[1][row][0];
      f32x4 qv = *(const f32x4*)&lstat[1][row][4];
      float ss = sv[0] + sv[1] + sv[2] + sv[3];
      float qq = qv[0] + qv[1] + qv[2] + qv[3];
      float mu = ss * (1.f / 256.f);
      mean1[r] = mu; rstd1[r] = rsqrtf(qq * (1.f / 256.f) - mu * mu + 1e-5f);
      sv = *(const f32x4*)&lstat[0][row][0];
      qv = *(const f32x4*)&lstat[0][row][4];
      ss = sv[0] + sv[1] + sv[2] + sv[3];
      qq = qv[0] + qv[1] + qv[2] + qv[3];
      mu = ss * (1.f / 256.f);
      mean0[r] = mu; rstd0[r] = rsqrtf(qq * (1.f / 256.f) - mu * mu + 1e-5f);
    }
#pragma unroll
    for (int fn = 0; fn < 4; ++fn) {
      int col = wn * 64 + fn * 16 + cl;
      u16 hb[4];
#pragma unroll
      for (int r = 0; r < 4; ++r) {
        float h = fmaxf((accU[fm][fn][r] - mean1[r]) * rstd1[r] * g_r[1][fn] + bt_r[1][fn], 0.f);
        int row = fm * 16 + rl * 4 + r;
        lsA[row * 256 + (((col >> 3) ^ (row & 7)) << 3) + (col & 7)] = f2bf(h);
        float hp = fmaxf((accP[fm][fn][r] - mean0[r]) * rstd0[r] * g_r[0][fn] + bt_r[0][fn], 0.f);
        hb[r] = f2bf(hp);
      }
      hp_pk[fm][fn][0] = (uint32_t)hb[0] | ((uint32_t)hb[1] << 16);
      hp_pk[fm][fn][1] = (uint32_t)hb[2] | ((uint32_t)hb[3] << 16);
    }
  }
  __syncthreads();                                   // B3 (Hu visible)

  f32x4 gU[4][4], gP[4][4];
#pragma unroll
  for (int i = 0; i < 4; ++i)
#pragma unroll
    for (int j = 0; j < 4; ++j) { gU[i][j] = zero; gP[i][j] = zero; }

#define GEMM2(BR, gacc)                                                        \
  _Pragma("unroll")                                                            \
  for (int step = 0; step < 8; ++step) {                                       \
    bf16x8 aF[4], bF[4];                                                       \
    _Pragma("unroll")                                                          \
    for (int f = 0; f < 4; ++f) {                                              \
      int row = f * 16 + cl;                                                   \
      aF[f] = *(const bf16x8*)(lsA + row * 256 +                               \
                               (((step * 4 + rl) ^ (row & 7)) << 3));          \
      int ng = (BR) * 16 + wn * 4 + f;                                         \
      bF[f] = *(const bf16x8*)(W2pk + (size_t)((ng * 8 + step) * 64 + lane) * 8); \
    }                                                                          \
    _Pragma("unroll")                                                          \
    for (int fm = 0; fm < 4; ++fm)                                             \
      _Pragma("unroll")                                                        \
      for (int fn = 0; fn < 4; ++fn)                                           \
        gacc[fm][fn] = __builtin_amdgcn_mfma_f32_16x16x32_bf16(                \
            aF[fm], bF[fn], gacc[fm][fn], 0, 0, 0);                            \
  }

  GEMM2(1, gU)
  __syncthreads();                                   // B4 (Hu reads done)

  // --- write Hp, then GEMM2 for P branch
#pragma unroll
  for (int fm = 0; fm < 4; ++fm)
#pragma unroll
    for (int fn = 0; fn < 4; ++fn) {
      int col = wn * 64 + fn * 16 + cl;
#pragma unroll
      for (int r = 0; r < 4; ++r) {
        int row = fm * 16 + rl * 4 + r;
        u16 hb = (u16)(hp_pk[fm][fn][r >> 1] >> ((r & 1) * 16));
        lsA[row * 256 + (((col >> 3) ^ (row & 7)) << 3) + (col & 7)] = hb;
      }
    }
  __syncthreads();                                   // B5

  GEMM2(0, gP)
#undef GEMM2

  // --- epilogue: out = slots + gp*gu
  float b2p[4], b2u[4];
#pragma unroll
  for (int fn = 0; fn < 4; ++fn) {
    int col = wn * 64 + fn * 16 + cl;
    b2p[fn] = pb2[col]; b2u[fn] = ub2[col];
  }
#pragma unroll
  for (int fm = 0; fm < 4; ++fm)
#pragma unroll
    for (int fn = 0; fn < 4; ++fn) {
      int col = wn * 64 + fn * 16 + cl;
#pragma unroll
      for (int r = 0; r < 4; ++r) {
        int row = blockRow + fm * 16 + rl * 4 + r;
        size_t idx = (size_t)row * 256 + col;
        float gp = gP[fm][fn][r] + b2p[fn];
        float gu = gU[fm][fn][r] + b2u[fn];
        outp[idx] = slots[idx] + gp * gu;
      }
    }
}

// ---------------------------------------------------------------------------
// host launcher
// ---------------------------------------------------------------------------
extern "C" void kernel_launch(void* const* d_in, const int* in_sizes, int n_in,
                              void* d_out, int out_size, void* d_ws, size_t ws_size,
                              hipStream_t stream) {
  const float* inst  = (const float*)d_in[0];
  const float* slots = (const float*)d_in[1];
  const float* Wfc   = (const float*)d_in[2];
  const float* bfc   = (const float*)d_in[3];
  const float* Wfp   = (const float*)d_in[4];
  const float* bfp   = (const float*)d_in[5];
  const float* Kc    = (const float*)d_in[6];
  const float* Vc    = (const float*)d_in[7];
  const float* Kp    = (const float*)d_in[8];
  const float* Vp    = (const float*)d_in[9];
  const float* pW1   = (const float*)d_in[10];
  const float* pb1   = (const float*)d_in[11];
  const float* pg    = (const float*)d_in[12];
  const float* pbt   = (const float*)d_in[13];
  const float* pW2   = (const float*)d_in[14];
  const float* pb2   = (const float*)d_in[15];
  const float* uW1   = (const float*)d_in[16];
  const float* ub1   = (const float*)d_in[17];
  const float* ug    = (const float*)d_in[18];
  const float* ubt   = (const float*)d_in[19];
  const float* uW2   = (const float*)d_in[20];
  const float* ub2   = (const float*)d_in[21];
  float* out = (float*)d_out;
  char*  ws  = (char*)d_ws;

  // ---- workspace layout (bytes) ----
  const size_t OFF_INST  = 0;                         // [4096][768] bf16
  const size_t OFF_KC    = OFF_INST  + 6291456;       // [512][768] bf16 x2
  const size_t OFF_KP    = OFF_KC    + 786432;
  const size_t OFF_WFCB  = OFF_KP    + 786432;        // [768][768] bf16 x2
  const size_t OFF_WFPB  = OFF_WFCB  + 1179648;
  const size_t OFF_VCB   = OFF_WFPB  + 1179648;       // [512][768] bf16 x2
  const size_t OFF_VPB   = OFF_VCB   + 786432;
  const size_t OFF_W1TP  = OFF_VPB   + 786432;        // [256][1024] bf16 x2
  const size_t OFF_W1TU  = OFF_W1TP  + 524288;
  const size_t OFF_W1PK  = OFF_W1TU  + 524288;        // [2][16][8][64][8] bf16
  const size_t OFF_W2PK  = OFF_W1PK  + 262144;
  const size_t OFF_KW    = OFF_W2PK  + 262144;        // [2][512][768] bf16
  const size_t OFF_VW1   = OFF_KW    + 1572864;       // [2][256][512] bf16
  const size_t OFF_SB    = OFF_VW1   + 524288;        // [2][512] f32
  const size_t OFF_T     = OFF_SB    + 4096;          // [2][4096][256] f32
  const size_t OFF_SC    = OFF_T     + 8388608;       // [2][4096][512] f32
  const size_t OFF_P     = OFF_SC    + 16777216;      // [2][4096][512] bf16

  u16*   instb = (u16*)(ws + OFF_INST);
  u16*   Kcb   = (u16*)(ws + OFF_KC);
  u16*   Kpb   = (u16*)(ws + OFF_KP);
  u16*   Wfcb  = (u16*)(ws + OFF_WFCB);
  u16*   Wfpb  = (u16*)(ws + OFF_WFPB);
  u16*   Vcb   = (u16*)(ws + OFF_VCB);
  u16*   Vpb   = (u16*)(ws + OFF_VPB);
  u16*   W1Tp  = (u16*)(ws + OFF_W1TP);
  u16*   W1Tu  = (u16*)(ws + OFF_W1TU);
  u16*   W1pk  = (u16*)(ws + OFF_W1PK);
  u16*   W2pk  = (u16*)(ws + OFF_W2PK);
  u16*   KWc   = (u16*)(ws + OFF_KW);
  u16*   KWp   = KWc + (size_t)NC * PP;
  u16*   VW1p  = (u16*)(ws + OFF_VW1);
  u16*   VW1u  = VW1p + (size_t)SLOT * NC;
  float* sb    = (float*)(ws + OFF_SB);
  float* t0    = (float*)(ws + OFF_T);
  float* t1    = t0 + (size_t)BB * SLOT;
  float* sc    = (float*)(ws + OFF_SC);
  u16*   Pb    = (u16*)(ws + OFF_P);

  // 1) all prep in one dispatch
  prep_all<<<dim3(6592), 256, 0, stream>>>(
      inst, Kc, Kp, Wfc, Wfp, Vc, Vp, pW1, uW1, pW2, uW2, bfc, bfp,
      instb, Kcb, Kpb, Wfcb, Wfpb, Vcb, Vpb, W1Tp, W1Tu, W1pk, W2pk, sb);

  // 2) KW = K @ Wf^T  and  VW1 = (W1part^T) @ V^T in one dispatch
  gemm_mixed<<<dim3(64), 256, 0, stream>>>(
      Kcb, Kpb, Wfcb, Wfpb, KWc, KWp, W1Tp, W1Tu, Vcb, Vpb, VW1p, VW1u);

  // 3) scores = inst @ KW^T -> f32 [2][4096][512]
  gemm_scores<<<dim3(32, 4, 2), 256, 0, stream>>>(instb, KWc, KWp, sc);

  // 4) P = softmax((sc+sb)*alpha) -> bf16
  softmax_rows<<<dim3(2048), 256, 0, stream>>>(sc, sb, Pb);

  // 5) t = P @ VW1 + b1 -> f32 [2][4096][256]
  gemm_t<<<dim3(32, 2, 2), 256, 0, stream>>>(Pb, VW1p, VW1u, pb1, ub1, t0, t1);

  // 6) fused back half
  fused_update<<<dim3(512), 256, 0, stream>>>(
      slots, t0, t1, W1pk, W2pk, pg, pbt, ug, ubt, pb2, ub2, out);

  (void)in_sizes; (void)n_in; (void)out_size; (void)ws_size;
}

// Round 5
// 118.672 us; speedup vs baseline: 1.6599x; 1.1088x over previous
//
#include <hip/hip_runtime.h>
#include <stdint.h>

#define BB    4096
#define KS    8
#define PP    768
#define SLOT  256
#define HID   256
#define NC    512
#define BKROWS (BB*KS)          // 32768
typedef unsigned short u16;
typedef short bf16x8 __attribute__((ext_vector_type(8)));
typedef float f32x4  __attribute__((ext_vector_type(4)));

__device__ __forceinline__ u16 f2bf(float x) {
  union { float f; uint32_t u; } v; v.f = x;
  return (u16)((v.u + 0x7FFFu + ((v.u >> 16) & 1u)) >> 16);
}

__device__ __forceinline__ void gload_lds16(u16* ldst, const u16* gsrc) {
  __builtin_amdgcn_global_load_lds(
      (const __attribute__((address_space(1))) void*)gsrc,
      (__attribute__((address_space(3))) void*)ldst, 16, 0, 0);
}

// ---------------------------------------------------------------------------
// Generic GEMM core: C[M,N] = A_bf16[M,K] @ Bt_bf16[N,K]^T (+ epilogue)
// BM=BN=128, BK=64, 4 waves. EPI: 0=f32, 2=bf16, 3=+bias f32  [verified R1-R4]
// ---------------------------------------------------------------------------
template<int EPI>
__device__ __forceinline__ void gemm_core(
    const u16* __restrict__ A, int lda,
    const u16* __restrict__ B, int ldb,
    const float* __restrict__ bias,
    void* __restrict__ out, int ldo, int K,
    int blockRow, int blockCol, u16* lsA, u16* lsB)
{
  const int tid  = threadIdx.x;
  const int w    = tid >> 6;
  const int lane = tid & 63;
  const int wm   = w >> 1, wn = w & 1;
  const int rl   = lane >> 4, cl = lane & 15;

  f32x4 acc[4][4];
  const f32x4 zero = {0.f, 0.f, 0.f, 0.f};
#pragma unroll
  for (int i = 0; i < 4; ++i)
#pragma unroll
    for (int j = 0; j < 4; ++j) acc[i][j] = zero;

  const u16* Ablk = A + (size_t)blockRow * lda;
  const u16* Bblk = B + (size_t)blockCol * ldb;

  for (int k0 = 0; k0 < K; k0 += 64) {
#pragma unroll
    for (int i = 0; i < 4; ++i) {
      int seg   = i * 4 + w;
      int off16 = seg * 64 + lane;
      int row   = off16 >> 3;
      int chunk = (off16 & 7) ^ (row & 7);
      gload_lds16(lsA + seg * 512, Ablk + (size_t)row * lda + k0 + chunk * 8);
      gload_lds16(lsB + seg * 512, Bblk + (size_t)row * ldb + k0 + chunk * 8);
    }
    __syncthreads();

#pragma unroll
    for (int ks = 0; ks < 2; ++ks) {
      bf16x8 aF[4], bF[4];
#pragma unroll
      for (int f = 0; f < 4; ++f) {
        int r  = wm * 64 + f * 16 + cl;
        int ca = ((ks * 4 + rl) ^ (r & 7)) * 8;
        aF[f] = *(const bf16x8*)(lsA + r * 64 + ca);
        int rn = wn * 64 + f * 16 + cl;
        int cb = ((ks * 4 + rl) ^ (rn & 7)) * 8;
        bF[f] = *(const bf16x8*)(lsB + rn * 64 + cb);
      }
#pragma unroll
      for (int fm = 0; fm < 4; ++fm)
#pragma unroll
        for (int fn = 0; fn < 4; ++fn)
          acc[fm][fn] = __builtin_amdgcn_mfma_f32_16x16x32_bf16(
              aF[fm], bF[fn], acc[fm][fn], 0, 0, 0);
    }
    __syncthreads();
  }

#pragma unroll
  for (int fm = 0; fm < 4; ++fm) {
#pragma unroll
    for (int fn = 0; fn < 4; ++fn) {
      f32x4 v = acc[fm][fn];
#pragma unroll
      for (int r = 0; r < 4; ++r) {
        int grow = blockRow + wm * 64 + fm * 16 + rl * 4 + r;
        int gcol = blockCol + wn * 64 + fn * 16 + cl;
        float x = v[r];
        if constexpr (EPI == 0) {
          ((float*)out)[(size_t)grow * ldo + gcol] = x;
        } else if constexpr (EPI == 2) {
          ((u16*)out)[(size_t)grow * ldo + gcol] = f2bf(x);
        } else if constexpr (EPI == 3) {
          x += bias[gcol];
          ((float*)out)[(size_t)grow * ldo + gcol] = x;
        }
      }
    }
  }
}

// ---------------------------------------------------------------------------
// prep_all: one dispatch for every cvt / transpose / frag-pack / sb gemv.
// ---------------------------------------------------------------------------
__device__ __forceinline__ void cvt_seg(const float* __restrict__ in,
                                        u16* __restrict__ outp, int b, int n4) {
  int i = b * 256 + threadIdx.x;
  if (i < n4) {
    float4 v = ((const float4*)in)[i];
    ushort4 o;
    o.x = f2bf(v.x); o.y = f2bf(v.y); o.z = f2bf(v.z); o.w = f2bf(v.w);
    ((ushort4*)outp)[i] = o;
  }
}

// frag-pack: dst[((br*16+ng)*8+step)*64 + lane][j] = src[step*32 + rl*8 + j][ng*16 + cl]
__device__ __forceinline__ void pack_seg(const float* __restrict__ s0,
                                         const float* __restrict__ s1,
                                         u16* __restrict__ dst, int b) {
  int br = b >> 4, ng = b & 15;
  const float* src = br ? s1 : s0;
  int w = threadIdx.x >> 6, lane = threadIdx.x & 63;
  int rl = lane >> 4, cl = lane & 15;
#pragma unroll
  for (int s = 0; s < 2; ++s) {
    int step = w * 2 + s;
    union { u16 u[8]; uint4 q; } o;
#pragma unroll
    for (int j = 0; j < 8; ++j)
      o.u[j] = f2bf(src[(size_t)(step * 32 + rl * 8 + j) * 256 + ng * 16 + cl]);
    *(uint4*)(dst + (size_t)(((br * 16 + ng) * 8 + step) * 64 + lane) * 8) = o.q;
  }
}

__global__ __launch_bounds__(256) void prep_all(
    const float* __restrict__ inst, const float* __restrict__ Kc,
    const float* __restrict__ Kp, const float* __restrict__ Wfc,
    const float* __restrict__ Wfp, const float* __restrict__ Vc,
    const float* __restrict__ Vp, const float* __restrict__ pW1,
    const float* __restrict__ uW1, const float* __restrict__ pW2,
    const float* __restrict__ uW2, const float* __restrict__ bfc,
    const float* __restrict__ bfp,
    u16* instb, u16* Kcb, u16* Kpb, u16* Wfcb, u16* Wfpb, u16* Vcb, u16* Vpb,
    u16* W1Tp, u16* W1Tu, u16* W1pk, u16* W2pk, float* sb)
{
  __shared__ float tile[32][33];
  int b = blockIdx.x;
  if (b < 3072)      { cvt_seg(inst, instb, b,        786432); return; }
  else if (b < 3456) { cvt_seg(Kc,   Kcb,   b - 3072,  98304); return; }
  else if (b < 3840) { cvt_seg(Kp,   Kpb,   b - 3456,  98304); return; }
  else if (b < 4416) { cvt_seg(Wfc,  Wfcb,  b - 3840, 147456); return; }
  else if (b < 4992) { cvt_seg(Wfp,  Wfpb,  b - 4416, 147456); return; }
  else if (b < 5376) { cvt_seg(Vc,   Vcb,   b - 4992,  98304); return; }
  else if (b < 5760) { cvt_seg(Vp,   Vpb,   b - 5376,  98304); return; }
  else if (b < 6272) {
    // transpose [1024][256] f32 -> [256][1024] bf16
    int bb = b - 5760;
    const float* in = (bb < 256) ? pW1 : uW1;
    u16* outp = (bb < 256) ? W1Tp : W1Tu;
    bb &= 255;
    int tc = (bb & 7) * 32, tr = (bb >> 3) * 32;
    int lx = threadIdx.x & 31, ly = threadIdx.x >> 5;
#pragma unroll
    for (int i = 0; i < 32; i += 8)
      tile[ly + i][lx] = in[(size_t)(tr + ly + i) * 256 + tc + lx];
    __syncthreads();
#pragma unroll
    for (int i = 0; i < 32; i += 8)
      outp[(size_t)(tc + ly + i) * 1024 + tr + lx] = f2bf(tile[lx][ly + i]);
    return;
  }
  else if (b < 6304) { pack_seg(pW1, uW1, W1pk, b - 6272); return; }
  else if (b < 6336) { pack_seg(pW2, uW2, W2pk, b - 6304); return; }
  else {
    int w = threadIdx.x >> 6, lane = threadIdx.x & 63;
    int row = (b - 6336) * 4 + w;
    int br = row >> 9, n = row & 511;
    const float* Kr = (br ? Kp : Kc) + (size_t)n * PP;
    const float* bf = br ? bfp : bfc;
    float s = 0.f;
#pragma unroll
    for (int j = 0; j < 12; ++j) s += Kr[lane + j * 64] * bf[lane + j * 64];
#pragma unroll
    for (int o = 32; o; o >>= 1) s += __shfl_xor(s, o);
    if (!lane) sb[row] = s;
  }
}

// ---------------------------------------------------------------------------
// merged small GEMMs
// ---------------------------------------------------------------------------
__global__ __launch_bounds__(256) void gemm_mixed(
    const u16* Kcb, const u16* Kpb, const u16* Wfcb, const u16* Wfpb,
    u16* KWc, u16* KWp,
    const u16* W1Tp, const u16* W1Tu, const u16* Vcb, const u16* Vpb,
    u16* VW1p, u16* VW1u)
{
  __shared__ u16 lsA[128 * 64];
  __shared__ u16 lsB[128 * 64];
  int b = blockIdx.x;
  if (b < 48) {
    int z = b / 24, r = b % 24;
    gemm_core<2>(z ? Kpb : Kcb, PP, z ? Wfpb : Wfcb, PP, nullptr,
                 z ? KWp : KWc, PP, PP, (r & 3) * 128, (r >> 2) * 128, lsA, lsB);
  } else {
    int c = b - 48, z = c / 8, r = c % 8;
    gemm_core<2>((z ? W1Tu : W1Tp) + 256, 1024, z ? Vpb : Vcb, PP, nullptr,
                 z ? VW1u : VW1p, NC, PP, (r & 1) * 128, (r >> 1) * 128, lsA, lsB);
  }
}

__global__ __launch_bounds__(256) void gemm_scores(
    const u16* instb, const u16* KWc, const u16* KWp, float* sc)
{
  __shared__ u16 lsA[128 * 64];
  __shared__ u16 lsB[128 * 64];
  int z = blockIdx.z;
  gemm_core<0>(instb, PP, z ? KWp : KWc, PP, nullptr,
               sc + (size_t)z * BB * NC, NC, PP,
               blockIdx.x * 128, blockIdx.y * 128, lsA, lsB);
}

__global__ __launch_bounds__(256) void gemm_t(
    const u16* Pb, const u16* VW1p, const u16* VW1u,
    const float* pb1, const float* ub1, float* t0, float* t1)
{
  __shared__ u16 lsA[128 * 64];
  __shared__ u16 lsB[128 * 64];
  int z = blockIdx.z;
  gemm_core<3>(Pb + (size_t)z * BB * NC, NC, z ? VW1u : VW1p, NC,
               z ? ub1 : pb1, z ? t1 : t0, SLOT, NC,
               blockIdx.x * 128, blockIdx.y * 128, lsA, lsB);
}

// ---------------------------------------------------------------------------
// softmax over rows of 512 with broadcast bias sb[n]; alpha folded
// ---------------------------------------------------------------------------
__global__ __launch_bounds__(256) void softmax_rows(const float* __restrict__ S,
                                                    const float* __restrict__ sb,
                                                    u16* __restrict__ Pp) {
  int w = threadIdx.x >> 6, lane = threadIdx.x & 63;
  size_t row = (size_t)blockIdx.x * 4 + w;
  const float* src = S + row * 512 + lane * 8;
  const float* sbr = sb + ((row >> 12) << 9) + lane * 8;
  float4 v0 = *(const float4*)src;
  float4 v1 = *(const float4*)(src + 4);
  float4 s0 = *(const float4*)sbr;
  float4 s1 = *(const float4*)(sbr + 4);
  float vv[8] = {v0.x + s0.x, v0.y + s0.y, v0.z + s0.z, v0.w + s0.w,
                 v1.x + s1.x, v1.y + s1.y, v1.z + s1.z, v1.w + s1.w};
  float m = vv[0];
#pragma unroll
  for (int j = 1; j < 8; ++j) m = fmaxf(m, vv[j]);
#pragma unroll
  for (int o = 32; o; o >>= 1) m = fmaxf(m, __shfl_xor(m, o));
  const float alpha = 0.03608439182435161f;   // 1/sqrt(768)
  float e[8], s = 0.f;
#pragma unroll
  for (int j = 0; j < 8; ++j) { e[j] = __expf((vv[j] - m) * alpha); s += e[j]; }
#pragma unroll
  for (int o = 32; o; o >>= 1) s += __shfl_xor(s, o);
  float inv = 1.f / s;
  union { u16 u[8]; uint4 q; } ou;
#pragma unroll
  for (int j = 0; j < 8; ++j) ou.u[j] = f2bf(e[j] * inv);
  *(uint4*)(Pp + row * 512 + lane * 8) = ou.q;
}

// ---------------------------------------------------------------------------
// FUSED back half v3: 512 threads = 8 waves (1M x 8N), M=64 rows/block,
// wave tile 64 rows x 32 cols -> acc = 64 VGPR for both branches.
// B-fragments from L2 (frag-packed W1pk/W2pk). accP/accU reused as gP/gU.
// LDS: one 32KB tile (slots -> Hu -> Hp) + 9KB stats. 6 barriers.
// __launch_bounds__(512,4): VGPR<=128 -> 4 waves/SIMD (16 waves/CU).
// ---------------------------------------------------------------------------
__global__ __launch_bounds__(512, 4) void fused_update(
    const float* __restrict__ slots,
    const float* __restrict__ t0, const float* __restrict__ t1,
    const u16* __restrict__ W1pk, const u16* __restrict__ W2pk,
    const float* __restrict__ pg, const float* __restrict__ pbt,
    const float* __restrict__ ug, const float* __restrict__ ubt,
    const float* __restrict__ pb2, const float* __restrict__ ub2,
    float* __restrict__ outp)
{
  __shared__ u16 lsA[64 * 256];        // 32 KB: slots tile -> Hu -> Hp
  __shared__ float lstat[2][64][16];   //  8 KB partial sums/sumsq per wave
  __shared__ float lfin[2][64][2];     //  1 KB mean/rstd

  const int tid = threadIdx.x, wn = tid >> 6, lane = tid & 63;
  const int rl = lane >> 4, cl = lane & 15;
  const int blockRow = blockIdx.x * 64;

  // --- stage slots f32 -> bf16, swizzled
#pragma unroll
  for (int it = 0; it < 8; ++it) {
    int L = it * 512 + tid;
    int row = L >> 6, qc = L & 63;
    float4 v = *(const float4*)(slots + (size_t)(blockRow + row) * 256 + qc * 4);
    ushort4 b; b.x = f2bf(v.x); b.y = f2bf(v.y); b.z = f2bf(v.z); b.w = f2bf(v.w);
    int chunk = qc >> 1, half = qc & 1;
    *(ushort4*)(lsA + row * 256 + (((chunk ^ (row & 7)) << 3) + half * 4)) = b;
  }
  __syncthreads();                                   // B1

  f32x4 accP[4][2], accU[4][2];
  const f32x4 zero = {0.f, 0.f, 0.f, 0.f};
#pragma unroll
  for (int i = 0; i < 4; ++i)
#pragma unroll
    for (int j = 0; j < 2; ++j) { accP[i][j] = zero; accU[i][j] = zero; }

  // --- GEMM1: K=256 (8 steps of 32), A from LDS, B from L2
#pragma unroll
  for (int step = 0; step < 8; ++step) {
    bf16x8 aF[4], bP[2], bU[2];
#pragma unroll
    for (int f = 0; f < 4; ++f) {
      int row = f * 16 + cl;
      aF[f] = *(const bf16x8*)(lsA + row * 256 + (((step * 4 + rl) ^ (row & 7)) << 3));
    }
#pragma unroll
    for (int f = 0; f < 2; ++f) {
      int ng = wn * 2 + f;
      bP[f] = *(const bf16x8*)(W1pk + (size_t)((ng * 8 + step) * 64 + lane) * 8);
      bU[f] = *(const bf16x8*)(W1pk + (size_t)(((16 + ng) * 8 + step) * 64 + lane) * 8);
    }
#pragma unroll
    for (int fm = 0; fm < 4; ++fm)
#pragma unroll
      for (int fn = 0; fn < 2; ++fn) {
        accP[fm][fn] = __builtin_amdgcn_mfma_f32_16x16x32_bf16(aF[fm], bP[fn], accP[fm][fn], 0, 0, 0);
        accU[fm][fn] = __builtin_amdgcn_mfma_f32_16x16x32_bf16(aF[fm], bU[fn], accU[fm][fn], 0, 0, 0);
      }
  }

  // --- t add (b1 folded into t)
#pragma unroll
  for (int fm = 0; fm < 4; ++fm) {
    size_t trr = (size_t)(blockIdx.x * 8 + fm * 2 + (rl >> 1)) * 256;
#pragma unroll
    for (int fn = 0; fn < 2; ++fn) {
      int col = wn * 32 + fn * 16 + cl;
      float tp = t0[trr + col], tu = t1[trr + col];
#pragma unroll
      for (int r = 0; r < 4; ++r) { accP[fm][fn][r] += tp; accU[fm][fn][r] += tu; }
    }
  }

  // --- LN partial stats: in-reg over fn, butterfly over cl, LDS over wn
#pragma unroll
  for (int fm = 0; fm < 4; ++fm) {
    f32x4 s  = accP[fm][0] + accP[fm][1];
    f32x4 q  = accP[fm][0] * accP[fm][0] + accP[fm][1] * accP[fm][1];
    f32x4 su = accU[fm][0] + accU[fm][1];
    f32x4 qu = accU[fm][0] * accU[fm][0] + accU[fm][1] * accU[fm][1];
#pragma unroll
    for (int o = 1; o < 16; o <<= 1) {
#pragma unroll
      for (int r = 0; r < 4; ++r) {
        s[r]  += __shfl_xor(s[r],  o);
        q[r]  += __shfl_xor(q[r],  o);
        su[r] += __shfl_xor(su[r], o);
        qu[r] += __shfl_xor(qu[r], o);
      }
    }
    if (cl == 0) {
#pragma unroll
      for (int r = 0; r < 4; ++r) {
        int row = fm * 16 + rl * 4 + r;
        lstat[0][row][wn]     = s[r];
        lstat[0][row][8 + wn] = q[r];
        lstat[1][row][wn]     = su[r];
        lstat[1][row][8 + wn] = qu[r];
      }
    }
  }
  __syncthreads();                                   // B2

  // --- finalize stats (wave 0 only): mean/rstd per row per branch
  if (tid < 64) {
#pragma unroll
    for (int br = 0; br < 2; ++br) {
      f32x4 a = *(const f32x4*)&lstat[br][tid][0];
      f32x4 b = *(const f32x4*)&lstat[br][tid][4];
      f32x4 c = *(const f32x4*)&lstat[br][tid][8];
      f32x4 d = *(const f32x4*)&lstat[br][tid][12];
      float ss = a[0] + a[1] + a[2] + a[3] + b[0] + b[1] + b[2] + b[3];
      float qq = c[0] + c[1] + c[2] + c[3] + d[0] + d[1] + d[2] + d[3];
      float mu = ss * (1.f / 256.f);
      lfin[br][tid][0] = mu;
      lfin[br][tid][1] = rsqrtf(qq * (1.f / 256.f) - mu * mu + 1e-5f);
    }
  }
  __syncthreads();                                   // B2b

  float g0v[2], bt0v[2], g1v[2], bt1v[2];
#pragma unroll
  for (int fn = 0; fn < 2; ++fn) {
    int col = wn * 32 + fn * 16 + cl;
    g0v[fn] = pg[col]; bt0v[fn] = pbt[col];
    g1v[fn] = ug[col]; bt1v[fn] = ubt[col];
  }

  // --- normalize: Hu -> lsA (swizzled), Hp -> packed regs
  uint32_t hp_pk[4][2][2];
#pragma unroll
  for (int fm = 0; fm < 4; ++fm) {
    float mean0[4], rstd0[4], mean1[4], rstd1[4];
#pragma unroll
    for (int r = 0; r < 4; ++r) {
      int row = fm * 16 + rl * 4 + r;
      mean1[r] = lfin[1][row][0]; rstd1[r] = lfin[1][row][1];
      mean0[r] = lfin[0][row][0]; rstd0[r] = lfin[0][row][1];
    }
#pragma unroll
    for (int fn = 0; fn < 2; ++fn) {
      int col = wn * 32 + fn * 16 + cl;
      u16 hb[4];
#pragma unroll
      for (int r = 0; r < 4; ++r) {
        int row = fm * 16 + rl * 4 + r;
        float h = fmaxf((accU[fm][fn][r] - mean1[r]) * rstd1[r] * g1v[fn] + bt1v[fn], 0.f);
        lsA[row * 256 + (((col >> 3) ^ (row & 7)) << 3) + (col & 7)] = f2bf(h);
        float hp = fmaxf((accP[fm][fn][r] - mean0[r]) * rstd0[r] * g0v[fn] + bt0v[fn], 0.f);
        hb[r] = f2bf(hp);
      }
      hp_pk[fm][fn][0] = (uint32_t)hb[0] | ((uint32_t)hb[1] << 16);
      hp_pk[fm][fn][1] = (uint32_t)hb[2] | ((uint32_t)hb[3] << 16);
    }
  }
  // reuse accumulators as gate accumulators
#pragma unroll
  for (int i = 0; i < 4; ++i)
#pragma unroll
    for (int j = 0; j < 2; ++j) { accP[i][j] = zero; accU[i][j] = zero; }
  __syncthreads();                                   // B3 (Hu visible)

  // --- GEMM2-U: gate_u = Hu @ W2u  (into accU)
#pragma unroll
  for (int step = 0; step < 8; ++step) {
    bf16x8 aF[4], bF[2];
#pragma unroll
    for (int f = 0; f < 4; ++f) {
      int row = f * 16 + cl;
      aF[f] = *(const bf16x8*)(lsA + row * 256 + (((step * 4 + rl) ^ (row & 7)) << 3));
    }
#pragma unroll
    for (int f = 0; f < 2; ++f) {
      int ng = 16 + wn * 2 + f;
      bF[f] = *(const bf16x8*)(W2pk + (size_t)((ng * 8 + step) * 64 + lane) * 8);
    }
#pragma unroll
    for (int fm = 0; fm < 4; ++fm)
#pragma unroll
      for (int fn = 0; fn < 2; ++fn)
        accU[fm][fn] = __builtin_amdgcn_mfma_f32_16x16x32_bf16(aF[fm], bF[fn], accU[fm][fn], 0, 0, 0);
  }
  __syncthreads();                                   // B4 (Hu reads done)

  // --- write Hp
#pragma unroll
  for (int fm = 0; fm < 4; ++fm)
#pragma unroll
    for (int fn = 0; fn < 2; ++fn) {
      int col = wn * 32 + fn * 16 + cl;
#pragma unroll
      for (int r = 0; r < 4; ++r) {
        int row = fm * 16 + rl * 4 + r;
        u16 hb = (u16)(hp_pk[fm][fn][r >> 1] >> ((r & 1) * 16));
        lsA[row * 256 + (((col >> 3) ^ (row & 7)) << 3) + (col & 7)] = hb;
      }
    }
  __syncthreads();                                   // B5

  // --- GEMM2-P: gate_p = Hp @ W2p  (into accP)
#pragma unroll
  for (int step = 0; step < 8; ++step) {
    bf16x8 aF[4], bF[2];
#pragma unroll
    for (int f = 0; f < 4; ++f) {
      int row = f * 16 + cl;
      aF[f] = *(const bf16x8*)(lsA + row * 256 + (((step * 4 + rl) ^ (row & 7)) << 3));
    }
#pragma unroll
    for (int f = 0; f < 2; ++f) {
      int ng = wn * 2 + f;
      bF[f] = *(const bf16x8*)(W2pk + (size_t)((ng * 8 + step) * 64 + lane) * 8);
    }
#pragma unroll
    for (int fm = 0; fm < 4; ++fm)
#pragma unroll
      for (int fn = 0; fn < 2; ++fn)
        accP[fm][fn] = __builtin_amdgcn_mfma_f32_16x16x32_bf16(aF[fm], bF[fn], accP[fm][fn], 0, 0, 0);
  }

  // --- epilogue: out = slots + gp*gu
  float b2p[2], b2u[2];
#pragma unroll
  for (int fn = 0; fn < 2; ++fn) {
    int col = wn * 32 + fn * 16 + cl;
    b2p[fn] = pb2[col]; b2u[fn] = ub2[col];
  }
#pragma unroll
  for (int fm = 0; fm < 4; ++fm)
#pragma unroll
    for (int fn = 0; fn < 2; ++fn) {
      int col = wn * 32 + fn * 16 + cl;
#pragma unroll
      for (int r = 0; r < 4; ++r) {
        int row = blockRow + fm * 16 + rl * 4 + r;
        size_t idx = (size_t)row * 256 + col;
        float gp = accP[fm][fn][r] + b2p[fn];
        float gu = accU[fm][fn][r] + b2u[fn];
        outp[idx] = slots[idx] + gp * gu;
      }
    }
}

// ---------------------------------------------------------------------------
// host launcher
// ---------------------------------------------------------------------------
extern "C" void kernel_launch(void* const* d_in, const int* in_sizes, int n_in,
                              void* d_out, int out_size, void* d_ws, size_t ws_size,
                              hipStream_t stream) {
  const float* inst  = (const float*)d_in[0];
  const float* slots = (const float*)d_in[1];
  const float* Wfc   = (const float*)d_in[2];
  const float* bfc   = (const float*)d_in[3];
  const float* Wfp   = (const float*)d_in[4];
  const float* bfp   = (const float*)d_in[5];
  const float* Kc    = (const float*)d_in[6];
  const float* Vc    = (const float*)d_in[7];
  const float* Kp    = (const float*)d_in[8];
  const float* Vp    = (const float*)d_in[9];
  const float* pW1   = (const float*)d_in[10];
  const float* pb1   = (const float*)d_in[11];
  const float* pg    = (const float*)d_in[12];
  const float* pbt   = (const float*)d_in[13];
  const float* pW2   = (const float*)d_in[14];
  const float* pb2   = (const float*)d_in[15];
  const float* uW1   = (const float*)d_in[16];
  const float* ub1   = (const float*)d_in[17];
  const float* ug    = (const float*)d_in[18];
  const float* ubt   = (const float*)d_in[19];
  const float* uW2   = (const float*)d_in[20];
  const float* ub2   = (const float*)d_in[21];
  float* out = (float*)d_out;
  char*  ws  = (char*)d_ws;

  // ---- workspace layout (bytes) ----
  const size_t OFF_INST  = 0;                         // [4096][768] bf16
  const size_t OFF_KC    = OFF_INST  + 6291456;       // [512][768] bf16 x2
  const size_t OFF_KP    = OFF_KC    + 786432;
  const size_t OFF_WFCB  = OFF_KP    + 786432;        // [768][768] bf16 x2
  const size_t OFF_WFPB  = OFF_WFCB  + 1179648;
  const size_t OFF_VCB   = OFF_WFPB  + 1179648;       // [512][768] bf16 x2
  const size_t OFF_VPB   = OFF_VCB   + 786432;
  const size_t OFF_W1TP  = OFF_VPB   + 786432;        // [256][1024] bf16 x2
  const size_t OFF_W1TU  = OFF_W1TP  + 524288;
  const size_t OFF_W1PK  = OFF_W1TU  + 524288;        // [2][16][8][64][8] bf16
  const size_t OFF_W2PK  = OFF_W1PK  + 262144;
  const size_t OFF_KW    = OFF_W2PK  + 262144;        // [2][512][768] bf16
  const size_t OFF_VW1   = OFF_KW    + 1572864;       // [2][256][512] bf16
  const size_t OFF_SB    = OFF_VW1   + 524288;        // [2][512] f32
  const size_t OFF_T     = OFF_SB    + 4096;          // [2][4096][256] f32
  const size_t OFF_SC    = OFF_T     + 8388608;       // [2][4096][512] f32
  const size_t OFF_P     = OFF_SC    + 16777216;      // [2][4096][512] bf16

  u16*   instb = (u16*)(ws + OFF_INST);
  u16*   Kcb   = (u16*)(ws + OFF_KC);
  u16*   Kpb   = (u16*)(ws + OFF_KP);
  u16*   Wfcb  = (u16*)(ws + OFF_WFCB);
  u16*   Wfpb  = (u16*)(ws + OFF_WFPB);
  u16*   Vcb   = (u16*)(ws + OFF_VCB);
  u16*   Vpb   = (u16*)(ws + OFF_VPB);
  u16*   W1Tp  = (u16*)(ws + OFF_W1TP);
  u16*   W1Tu  = (u16*)(ws + OFF_W1TU);
  u16*   W1pk  = (u16*)(ws + OFF_W1PK);
  u16*   W2pk  = (u16*)(ws + OFF_W2PK);
  u16*   KWc   = (u16*)(ws + OFF_KW);
  u16*   KWp   = KWc + (size_t)NC * PP;
  u16*   VW1p  = (u16*)(ws + OFF_VW1);
  u16*   VW1u  = VW1p + (size_t)SLOT * NC;
  float* sb    = (float*)(ws + OFF_SB);
  float* t0    = (float*)(ws + OFF_T);
  float* t1    = t0 + (size_t)BB * SLOT;
  float* sc    = (float*)(ws + OFF_SC);
  u16*   Pb    = (u16*)(ws + OFF_P);

  // 1) all prep in one dispatch
  prep_all<<<dim3(6592), 256, 0, stream>>>(
      inst, Kc, Kp, Wfc, Wfp, Vc, Vp, pW1, uW1, pW2, uW2, bfc, bfp,
      instb, Kcb, Kpb, Wfcb, Wfpb, Vcb, Vpb, W1Tp, W1Tu, W1pk, W2pk, sb);

  // 2) KW = K @ Wf^T  and  VW1 = (W1part^T) @ V^T in one dispatch
  gemm_mixed<<<dim3(64), 256, 0, stream>>>(
      Kcb, Kpb, Wfcb, Wfpb, KWc, KWp, W1Tp, W1Tu, Vcb, Vpb, VW1p, VW1u);

  // 3) scores = inst @ KW^T -> f32 [2][4096][512]
  gemm_scores<<<dim3(32, 4, 2), 256, 0, stream>>>(instb, KWc, KWp, sc);

  // 4) P = softmax((sc+sb)*alpha) -> bf16
  softmax_rows<<<dim3(2048), 256, 0, stream>>>(sc, sb, Pb);

  // 5) t = P @ VW1 + b1 -> f32 [2][4096][256]
  gemm_t<<<dim3(32, 2, 2), 256, 0, stream>>>(Pb, VW1p, VW1u, pb1, ub1, t0, t1);

  // 6) fused back half (512 blocks x 512 threads)
  fused_update<<<dim3(512), 512, 0, stream>>>(
      slots, t0, t1, W1pk, W2pk, pg, pbt, ug, ubt, pb2, ub2, out);

  (void)in_sizes; (void)n_in; (void)out_size; (void)ws_size;
}

// Round 6
// 113.543 us; speedup vs baseline: 1.7349x; 1.0452x over previous
//
#include <hip/hip_runtime.h>
#include <stdint.h>

#define BB    4096
#define KS    8
#define PP    768
#define SLOT  256
#define HID   256
#define NC    512
#define BKROWS (BB*KS)          // 32768
typedef unsigned short u16;
typedef short bf16x8 __attribute__((ext_vector_type(8)));
typedef float f32x4  __attribute__((ext_vector_type(4)));

__device__ __forceinline__ u16 f2bf(float x) {
  union { float f; uint32_t u; } v; v.f = x;
  return (u16)((v.u + 0x7FFFu + ((v.u >> 16) & 1u)) >> 16);
}

__device__ __forceinline__ void gload_lds16(u16* ldst, const u16* gsrc) {
  __builtin_amdgcn_global_load_lds(
      (const __attribute__((address_space(1))) void*)gsrc,
      (__attribute__((address_space(3))) void*)ldst, 16, 0, 0);
}

// ---------------------------------------------------------------------------
// Generic GEMM core: C[M,N] = A_bf16[M,K] @ Bt_bf16[N,K]^T (+ epilogue)
// BM=BN=128, BK=64, 4 waves. EPI: 0=f32, 2=bf16, 3=+bias f32  [verified R1-R5]
// ---------------------------------------------------------------------------
template<int EPI>
__device__ __forceinline__ void gemm_core(
    const u16* __restrict__ A, int lda,
    const u16* __restrict__ B, int ldb,
    const float* __restrict__ bias,
    void* __restrict__ out, int ldo, int K,
    int blockRow, int blockCol, u16* lsA, u16* lsB)
{
  const int tid  = threadIdx.x;
  const int w    = tid >> 6;
  const int lane = tid & 63;
  const int wm   = w >> 1, wn = w & 1;
  const int rl   = lane >> 4, cl = lane & 15;

  f32x4 acc[4][4];
  const f32x4 zero = {0.f, 0.f, 0.f, 0.f};
#pragma unroll
  for (int i = 0; i < 4; ++i)
#pragma unroll
    for (int j = 0; j < 4; ++j) acc[i][j] = zero;

  const u16* Ablk = A + (size_t)blockRow * lda;
  const u16* Bblk = B + (size_t)blockCol * ldb;

  for (int k0 = 0; k0 < K; k0 += 64) {
#pragma unroll
    for (int i = 0; i < 4; ++i) {
      int seg   = i * 4 + w;
      int off16 = seg * 64 + lane;
      int row   = off16 >> 3;
      int chunk = (off16 & 7) ^ (row & 7);
      gload_lds16(lsA + seg * 512, Ablk + (size_t)row * lda + k0 + chunk * 8);
      gload_lds16(lsB + seg * 512, Bblk + (size_t)row * ldb + k0 + chunk * 8);
    }
    __syncthreads();

#pragma unroll
    for (int ks = 0; ks < 2; ++ks) {
      bf16x8 aF[4], bF[4];
#pragma unroll
      for (int f = 0; f < 4; ++f) {
        int r  = wm * 64 + f * 16 + cl;
        int ca = ((ks * 4 + rl) ^ (r & 7)) * 8;
        aF[f] = *(const bf16x8*)(lsA + r * 64 + ca);
        int rn = wn * 64 + f * 16 + cl;
        int cb = ((ks * 4 + rl) ^ (rn & 7)) * 8;
        bF[f] = *(const bf16x8*)(lsB + rn * 64 + cb);
      }
#pragma unroll
      for (int fm = 0; fm < 4; ++fm)
#pragma unroll
        for (int fn = 0; fn < 4; ++fn)
          acc[fm][fn] = __builtin_amdgcn_mfma_f32_16x16x32_bf16(
              aF[fm], bF[fn], acc[fm][fn], 0, 0, 0);
    }
    __syncthreads();
  }

#pragma unroll
  for (int fm = 0; fm < 4; ++fm) {
#pragma unroll
    for (int fn = 0; fn < 4; ++fn) {
      f32x4 v = acc[fm][fn];
#pragma unroll
      for (int r = 0; r < 4; ++r) {
        int grow = blockRow + wm * 64 + fm * 16 + rl * 4 + r;
        int gcol = blockCol + wn * 64 + fn * 16 + cl;
        float x = v[r];
        if constexpr (EPI == 0) {
          ((float*)out)[(size_t)grow * ldo + gcol] = x;
        } else if constexpr (EPI == 2) {
          ((u16*)out)[(size_t)grow * ldo + gcol] = f2bf(x);
        } else if constexpr (EPI == 3) {
          x += bias[gcol];
          ((float*)out)[(size_t)grow * ldo + gcol] = x;
        }
      }
    }
  }
}

// ---------------------------------------------------------------------------
// prep_all: one dispatch for every cvt / transpose / frag-pack / sb gemv.
// ---------------------------------------------------------------------------
__device__ __forceinline__ void cvt_seg(const float* __restrict__ in,
                                        u16* __restrict__ outp, int b, int n4) {
  int i = b * 256 + threadIdx.x;
  if (i < n4) {
    float4 v = ((const float4*)in)[i];
    ushort4 o;
    o.x = f2bf(v.x); o.y = f2bf(v.y); o.z = f2bf(v.z); o.w = f2bf(v.w);
    ((ushort4*)outp)[i] = o;
  }
}

// frag-pack: dst[((br*16+ng)*8+step)*64 + lane][j] = src[step*32 + rl*8 + j][ng*16 + cl]
__device__ __forceinline__ void pack_seg(const float* __restrict__ s0,
                                         const float* __restrict__ s1,
                                         u16* __restrict__ dst, int b) {
  int br = b >> 4, ng = b & 15;
  const float* src = br ? s1 : s0;
  int w = threadIdx.x >> 6, lane = threadIdx.x & 63;
  int rl = lane >> 4, cl = lane & 15;
#pragma unroll
  for (int s = 0; s < 2; ++s) {
    int step = w * 2 + s;
    union { u16 u[8]; uint4 q; } o;
#pragma unroll
    for (int j = 0; j < 8; ++j)
      o.u[j] = f2bf(src[(size_t)(step * 32 + rl * 8 + j) * 256 + ng * 16 + cl]);
    *(uint4*)(dst + (size_t)(((br * 16 + ng) * 8 + step) * 64 + lane) * 8) = o.q;
  }
}

__global__ __launch_bounds__(256) void prep_all(
    const float* __restrict__ inst, const float* __restrict__ Kc,
    const float* __restrict__ Kp, const float* __restrict__ Wfc,
    const float* __restrict__ Wfp, const float* __restrict__ Vc,
    const float* __restrict__ Vp, const float* __restrict__ pW1,
    const float* __restrict__ uW1, const float* __restrict__ pW2,
    const float* __restrict__ uW2, const float* __restrict__ bfc,
    const float* __restrict__ bfp,
    u16* instb, u16* Kcb, u16* Kpb, u16* Wfcb, u16* Wfpb, u16* Vcb, u16* Vpb,
    u16* W1Tp, u16* W1Tu, u16* W1pk, u16* W2pk, float* sb)
{
  __shared__ float tile[32][33];
  int b = blockIdx.x;
  if (b < 3072)      { cvt_seg(inst, instb, b,        786432); return; }
  else if (b < 3456) { cvt_seg(Kc,   Kcb,   b - 3072,  98304); return; }
  else if (b < 3840) { cvt_seg(Kp,   Kpb,   b - 3456,  98304); return; }
  else if (b < 4416) { cvt_seg(Wfc,  Wfcb,  b - 3840, 147456); return; }
  else if (b < 4992) { cvt_seg(Wfp,  Wfpb,  b - 4416, 147456); return; }
  else if (b < 5376) { cvt_seg(Vc,   Vcb,   b - 4992,  98304); return; }
  else if (b < 5760) { cvt_seg(Vp,   Vpb,   b - 5376,  98304); return; }
  else if (b < 6272) {
    // transpose [1024][256] f32 -> [256][1024] bf16
    int bb = b - 5760;
    const float* in = (bb < 256) ? pW1 : uW1;
    u16* outp = (bb < 256) ? W1Tp : W1Tu;
    bb &= 255;
    int tc = (bb & 7) * 32, tr = (bb >> 3) * 32;
    int lx = threadIdx.x & 31, ly = threadIdx.x >> 5;
#pragma unroll
    for (int i = 0; i < 32; i += 8)
      tile[ly + i][lx] = in[(size_t)(tr + ly + i) * 256 + tc + lx];
    __syncthreads();
#pragma unroll
    for (int i = 0; i < 32; i += 8)
      outp[(size_t)(tc + ly + i) * 1024 + tr + lx] = f2bf(tile[lx][ly + i]);
    return;
  }
  else if (b < 6304) { pack_seg(pW1, uW1, W1pk, b - 6272); return; }
  else if (b < 6336) { pack_seg(pW2, uW2, W2pk, b - 6304); return; }
  else {
    int w = threadIdx.x >> 6, lane = threadIdx.x & 63;
    int row = (b - 6336) * 4 + w;
    int br = row >> 9, n = row & 511;
    const float* Kr = (br ? Kp : Kc) + (size_t)n * PP;
    const float* bf = br ? bfp : bfc;
    float s = 0.f;
#pragma unroll
    for (int j = 0; j < 12; ++j) s += Kr[lane + j * 64] * bf[lane + j * 64];
#pragma unroll
    for (int o = 32; o; o >>= 1) s += __shfl_xor(s, o);
    if (!lane) sb[row] = s;
  }
}

// ---------------------------------------------------------------------------
// merged small GEMMs
// ---------------------------------------------------------------------------
__global__ __launch_bounds__(256) void gemm_mixed(
    const u16* Kcb, const u16* Kpb, const u16* Wfcb, const u16* Wfpb,
    u16* KWc, u16* KWp,
    const u16* W1Tp, const u16* W1Tu, const u16* Vcb, const u16* Vpb,
    u16* VW1p, u16* VW1u)
{
  __shared__ u16 lsA[128 * 64];
  __shared__ u16 lsB[128 * 64];
  int b = blockIdx.x;
  if (b < 48) {
    int z = b / 24, r = b % 24;
    gemm_core<2>(z ? Kpb : Kcb, PP, z ? Wfpb : Wfcb, PP, nullptr,
                 z ? KWp : KWc, PP, PP, (r & 3) * 128, (r >> 2) * 128, lsA, lsB);
  } else {
    int c = b - 48, z = c / 8, r = c % 8;
    gemm_core<2>((z ? W1Tu : W1Tp) + 256, 1024, z ? Vpb : Vcb, PP, nullptr,
                 z ? VW1u : VW1p, NC, PP, (r & 1) * 128, (r >> 1) * 128, lsA, lsB);
  }
}

__global__ __launch_bounds__(256) void gemm_scores(
    const u16* instb, const u16* KWc, const u16* KWp, float* sc)
{
  __shared__ u16 lsA[128 * 64];
  __shared__ u16 lsB[128 * 64];
  int z = blockIdx.z;
  gemm_core<0>(instb, PP, z ? KWp : KWc, PP, nullptr,
               sc + (size_t)z * BB * NC, NC, PP,
               blockIdx.x * 128, blockIdx.y * 128, lsA, lsB);
}

__global__ __launch_bounds__(256) void gemm_t(
    const u16* Pb, const u16* VW1p, const u16* VW1u,
    const float* pb1, const float* ub1, float* t0, float* t1)
{
  __shared__ u16 lsA[128 * 64];
  __shared__ u16 lsB[128 * 64];
  int z = blockIdx.z;
  gemm_core<3>(Pb + (size_t)z * BB * NC, NC, z ? VW1u : VW1p, NC,
               z ? ub1 : pb1, z ? t1 : t0, SLOT, NC,
               blockIdx.x * 128, blockIdx.y * 128, lsA, lsB);
}

// ---------------------------------------------------------------------------
// softmax over rows of 512 with broadcast bias sb[n]; alpha folded
// ---------------------------------------------------------------------------
__global__ __launch_bounds__(256) void softmax_rows(const float* __restrict__ S,
                                                    const float* __restrict__ sb,
                                                    u16* __restrict__ Pp) {
  int w = threadIdx.x >> 6, lane = threadIdx.x & 63;
  size_t row = (size_t)blockIdx.x * 4 + w;
  const float* src = S + row * 512 + lane * 8;
  const float* sbr = sb + ((row >> 12) << 9) + lane * 8;
  float4 v0 = *(const float4*)src;
  float4 v1 = *(const float4*)(src + 4);
  float4 s0 = *(const float4*)sbr;
  float4 s1 = *(const float4*)(sbr + 4);
  float vv[8] = {v0.x + s0.x, v0.y + s0.y, v0.z + s0.z, v0.w + s0.w,
                 v1.x + s1.x, v1.y + s1.y, v1.z + s1.z, v1.w + s1.w};
  float m = vv[0];
#pragma unroll
  for (int j = 1; j < 8; ++j) m = fmaxf(m, vv[j]);
#pragma unroll
  for (int o = 32; o; o >>= 1) m = fmaxf(m, __shfl_xor(m, o));
  const float alpha = 0.03608439182435161f;   // 1/sqrt(768)
  float e[8], s = 0.f;
#pragma unroll
  for (int j = 0; j < 8; ++j) { e[j] = __expf((vv[j] - m) * alpha); s += e[j]; }
#pragma unroll
  for (int o = 32; o; o >>= 1) s += __shfl_xor(s, o);
  float inv = 1.f / s;
  union { u16 u[8]; uint4 q; } ou;
#pragma unroll
  for (int j = 0; j < 8; ++j) ou.u[j] = f2bf(e[j] * inv);
  *(uint4*)(Pp + row * 512 + lane * 8) = ou.q;
}

// ---------------------------------------------------------------------------
// FUSED back half v4: 1024 threads = 16 waves; waves 0-7 = P branch, 8-15 = U.
// Wave tile = 64 rows x 32 cols, ONE branch -> acc = 32 VGPR.
// B-fragments from L2 (frag-packed), ~50 spare regs for compiler prefetch.
// GEMM2-P and GEMM2-U run concurrently on different waves.
// Cross-branch gate exchange through the 64KB H-tile LDS (as f32).
// LDS: 64KB tiles + 9KB stats = 73KB. launch_bounds(1024,4) -> <=128 regs.
// ---------------------------------------------------------------------------
__global__ __launch_bounds__(1024, 4) void fused_update(
    const float* __restrict__ slots,
    const float* __restrict__ t0, const float* __restrict__ t1,
    const u16* __restrict__ W1pk, const u16* __restrict__ W2pk,
    const float* __restrict__ pg, const float* __restrict__ pbt,
    const float* __restrict__ ug, const float* __restrict__ ubt,
    const float* __restrict__ pb2, const float* __restrict__ ub2,
    float* __restrict__ outp)
{
  __shared__ u16 lsH[2][64 * 256];     // [0]: slots->Hp, [1]: Hu; also gate xchg (f32)
  __shared__ float lstat[2][64][16];   // partial sums/sumsq per branch
  __shared__ float lfin[2][64][2];     // mean/rstd

  const int tid = threadIdx.x;
  const int w = tid >> 6, br = w >> 3, wn = w & 7;
  const int lane = tid & 63, rl = lane >> 4, cl = lane & 15;
  const int blockRow = blockIdx.x * 64;

  u16* lsA = lsH[0];

  // --- stage slots f32 -> bf16 into lsA, swizzled (16B-chunk ^= row&7)
#pragma unroll
  for (int it = 0; it < 4; ++it) {
    int L = it * 1024 + tid;          // float4 index in [0,4096)
    int row = L >> 6, qc = L & 63;
    float4 v = *(const float4*)(slots + (size_t)(blockRow + row) * 256 + qc * 4);
    ushort4 b; b.x = f2bf(v.x); b.y = f2bf(v.y); b.z = f2bf(v.z); b.w = f2bf(v.w);
    int chunk = qc >> 1, half = qc & 1;
    *(ushort4*)(lsA + row * 256 + (((chunk ^ (row & 7)) << 3) + half * 4)) = b;
  }
  __syncthreads();                                   // B1

  // branch-specific pointers
  const u16*   Wpk1  = W1pk + (size_t)br * 65536;   // 16 ng * 8 step * 64 lane * 8
  const u16*   Wpk2  = W2pk + (size_t)br * 65536;
  const float* tsrc  = br ? t1 : t0;
  const float* gsrc  = br ? ug : pg;
  const float* btsrc = br ? ubt : pbt;
  const float* b2src = br ? ub2 : pb2;

  f32x4 acc[4][2];
  const f32x4 zero = {0.f, 0.f, 0.f, 0.f};
#pragma unroll
  for (int i = 0; i < 4; ++i)
#pragma unroll
    for (int j = 0; j < 2; ++j) acc[i][j] = zero;

  // --- GEMM1: K=256 (8 steps of 32), A from LDS, B from L2 (own branch)
#pragma unroll
  for (int step = 0; step < 8; ++step) {
    bf16x8 aF[4], bF[2];
#pragma unroll
    for (int f = 0; f < 4; ++f) {
      int row = f * 16 + cl;
      aF[f] = *(const bf16x8*)(lsA + row * 256 + (((step * 4 + rl) ^ (row & 7)) << 3));
    }
#pragma unroll
    for (int f = 0; f < 2; ++f) {
      int ng = wn * 2 + f;
      bF[f] = *(const bf16x8*)(Wpk1 + (size_t)((ng * 8 + step) * 64 + lane) * 8);
    }
#pragma unroll
    for (int fm = 0; fm < 4; ++fm)
#pragma unroll
      for (int fn = 0; fn < 2; ++fn)
        acc[fm][fn] = __builtin_amdgcn_mfma_f32_16x16x32_bf16(aF[fm], bF[fn], acc[fm][fn], 0, 0, 0);
  }

  // --- t add (b1 folded into t), own branch
#pragma unroll
  for (int fm = 0; fm < 4; ++fm) {
    size_t trr = (size_t)(blockIdx.x * 8 + fm * 2 + (rl >> 1)) * 256;
#pragma unroll
    for (int fn = 0; fn < 2; ++fn) {
      int col = wn * 32 + fn * 16 + cl;
      float tv = tsrc[trr + col];
#pragma unroll
      for (int r = 0; r < 4; ++r) acc[fm][fn][r] += tv;
    }
  }

  // --- LN partial stats (own branch): in-reg over fn, butterfly over cl
#pragma unroll
  for (int fm = 0; fm < 4; ++fm) {
    f32x4 s = acc[fm][0] + acc[fm][1];
    f32x4 q = acc[fm][0] * acc[fm][0] + acc[fm][1] * acc[fm][1];
#pragma unroll
    for (int o = 1; o < 16; o <<= 1) {
#pragma unroll
      for (int r = 0; r < 4; ++r) {
        s[r] += __shfl_xor(s[r], o);
        q[r] += __shfl_xor(q[r], o);
      }
    }
    if (cl == 0) {
#pragma unroll
      for (int r = 0; r < 4; ++r) {
        int row = fm * 16 + rl * 4 + r;
        lstat[br][row][wn]     = s[r];
        lstat[br][row][8 + wn] = q[r];
      }
    }
  }
  __syncthreads();                                   // B2

  // --- finalize stats: 128 threads handle (br,row)
  if (tid < 128) {
    int fb = tid >> 6, row = tid & 63;
    f32x4 a = *(const f32x4*)&lstat[fb][row][0];
    f32x4 b = *(const f32x4*)&lstat[fb][row][4];
    f32x4 c = *(const f32x4*)&lstat[fb][row][8];
    f32x4 d = *(const f32x4*)&lstat[fb][row][12];
    float ss = a[0] + a[1] + a[2] + a[3] + b[0] + b[1] + b[2] + b[3];
    float qq = c[0] + c[1] + c[2] + c[3] + d[0] + d[1] + d[2] + d[3];
    float mu = ss * (1.f / 256.f);
    lfin[fb][row][0] = mu;
    lfin[fb][row][1] = rsqrtf(qq * (1.f / 256.f) - mu * mu + 1e-5f);
  }
  __syncthreads();                                   // B2b

  float gv[2], btv[2], b2v[2];
#pragma unroll
  for (int fn = 0; fn < 2; ++fn) {
    int col = wn * 32 + fn * 16 + cl;
    gv[fn]  = gsrc[col];
    btv[fn] = btsrc[col];
    b2v[fn] = b2src[col];
  }

  // --- normalize own branch -> H bf16 into own tile (P: lsH[0], U: lsH[1])
  u16* hdst = lsH[br];
#pragma unroll
  for (int fm = 0; fm < 4; ++fm) {
    float mean[4], rstd[4];
#pragma unroll
    for (int r = 0; r < 4; ++r) {
      int row = fm * 16 + rl * 4 + r;
      mean[r] = lfin[br][row][0];
      rstd[r] = lfin[br][row][1];
    }
#pragma unroll
    for (int fn = 0; fn < 2; ++fn) {
      int col = wn * 32 + fn * 16 + cl;
#pragma unroll
      for (int r = 0; r < 4; ++r) {
        int row = fm * 16 + rl * 4 + r;
        float h = fmaxf((acc[fm][fn][r] - mean[r]) * rstd[r] * gv[fn] + btv[fn], 0.f);
        hdst[row * 256 + (((col >> 3) ^ (row & 7)) << 3) + (col & 7)] = f2bf(h);
      }
    }
  }
  // reuse acc as gate accumulator
#pragma unroll
  for (int i = 0; i < 4; ++i)
#pragma unroll
    for (int j = 0; j < 2; ++j) acc[i][j] = zero;
  __syncthreads();                                   // B3 (H tiles visible; lsA slots dead)

  // --- GEMM2: gate = H(own branch) @ W2(own branch)
  const u16* hsrc = lsH[br];
#pragma unroll
  for (int step = 0; step < 8; ++step) {
    bf16x8 aF[4], bF[2];
#pragma unroll
    for (int f = 0; f < 4; ++f) {
      int row = f * 16 + cl;
      aF[f] = *(const bf16x8*)(hsrc + row * 256 + (((step * 4 + rl) ^ (row & 7)) << 3));
    }
#pragma unroll
    for (int f = 0; f < 2; ++f) {
      int ng = wn * 2 + f;
      bF[f] = *(const bf16x8*)(Wpk2 + (size_t)((ng * 8 + step) * 64 + lane) * 8);
    }
#pragma unroll
    for (int fm = 0; fm < 4; ++fm)
#pragma unroll
      for (int fn = 0; fn < 2; ++fn)
        acc[fm][fn] = __builtin_amdgcn_mfma_f32_16x16x32_bf16(aF[fm], bF[fn], acc[fm][fn], 0, 0, 0);
  }
  __syncthreads();                                   // B4 (all H reads done)

  // --- gate exchange: P-waves write gp (f32) into lsH viewed as float[64][256]
  float* gbuf = (float*)&lsH[0][0];                  // 64 KB
  if (br == 0) {
#pragma unroll
    for (int fm = 0; fm < 4; ++fm)
#pragma unroll
      for (int fn = 0; fn < 2; ++fn) {
        int col = wn * 32 + fn * 16 + cl;
#pragma unroll
        for (int r = 0; r < 4; ++r) {
          int row = fm * 16 + rl * 4 + r;
          gbuf[row * 256 + (col ^ (rl << 4))] = acc[fm][fn][r] + b2v[fn];
        }
      }
  }
  __syncthreads();                                   // B5

  // --- U-waves combine: out = slots + gp*gu
  if (br == 1) {
#pragma unroll
    for (int fm = 0; fm < 4; ++fm)
#pragma unroll
      for (int fn = 0; fn < 2; ++fn) {
        int col = wn * 32 + fn * 16 + cl;
#pragma unroll
        for (int r = 0; r < 4; ++r) {
          int row = fm * 16 + rl * 4 + r;
          float gp = gbuf[row * 256 + (col ^ (rl << 4))];
          float gu = acc[fm][fn][r] + b2v[fn];
          size_t idx = (size_t)(blockRow + row) * 256 + col;
          outp[idx] = slots[idx] + gp * gu;
        }
      }
  }
}

// ---------------------------------------------------------------------------
// host launcher
// ---------------------------------------------------------------------------
extern "C" void kernel_launch(void* const* d_in, const int* in_sizes, int n_in,
                              void* d_out, int out_size, void* d_ws, size_t ws_size,
                              hipStream_t stream) {
  const float* inst  = (const float*)d_in[0];
  const float* slots = (const float*)d_in[1];
  const float* Wfc   = (const float*)d_in[2];
  const float* bfc   = (const float*)d_in[3];
  const float* Wfp   = (const float*)d_in[4];
  const float* bfp   = (const float*)d_in[5];
  const float* Kc    = (const float*)d_in[6];
  const float* Vc    = (const float*)d_in[7];
  const float* Kp    = (const float*)d_in[8];
  const float* Vp    = (const float*)d_in[9];
  const float* pW1   = (const float*)d_in[10];
  const float* pb1   = (const float*)d_in[11];
  const float* pg    = (const float*)d_in[12];
  const float* pbt   = (const float*)d_in[13];
  const float* pW2   = (const float*)d_in[14];
  const float* pb2   = (const float*)d_in[15];
  const float* uW1   = (const float*)d_in[16];
  const float* ub1   = (const float*)d_in[17];
  const float* ug    = (const float*)d_in[18];
  const float* ubt   = (const float*)d_in[19];
  const float* uW2   = (const float*)d_in[20];
  const float* ub2   = (const float*)d_in[21];
  float* out = (float*)d_out;
  char*  ws  = (char*)d_ws;

  // ---- workspace layout (bytes) ----
  const size_t OFF_INST  = 0;                         // [4096][768] bf16
  const size_t OFF_KC    = OFF_INST  + 6291456;       // [512][768] bf16 x2
  const size_t OFF_KP    = OFF_KC    + 786432;
  const size_t OFF_WFCB  = OFF_KP    + 786432;        // [768][768] bf16 x2
  const size_t OFF_WFPB  = OFF_WFCB  + 1179648;
  const size_t OFF_VCB   = OFF_WFPB  + 1179648;       // [512][768] bf16 x2
  const size_t OFF_VPB   = OFF_VCB   + 786432;
  const size_t OFF_W1TP  = OFF_VPB   + 786432;        // [256][1024] bf16 x2
  const size_t OFF_W1TU  = OFF_W1TP  + 524288;
  const size_t OFF_W1PK  = OFF_W1TU  + 524288;        // [2][16][8][64][8] bf16
  const size_t OFF_W2PK  = OFF_W1PK  + 262144;
  const size_t OFF_KW    = OFF_W2PK  + 262144;        // [2][512][768] bf16
  const size_t OFF_VW1   = OFF_KW    + 1572864;       // [2][256][512] bf16
  const size_t OFF_SB    = OFF_VW1   + 524288;        // [2][512] f32
  const size_t OFF_T     = OFF_SB    + 4096;          // [2][4096][256] f32
  const size_t OFF_SC    = OFF_T     + 8388608;       // [2][4096][512] f32
  const size_t OFF_P     = OFF_SC    + 16777216;      // [2][4096][512] bf16

  u16*   instb = (u16*)(ws + OFF_INST);
  u16*   Kcb   = (u16*)(ws + OFF_KC);
  u16*   Kpb   = (u16*)(ws + OFF_KP);
  u16*   Wfcb  = (u16*)(ws + OFF_WFCB);
  u16*   Wfpb  = (u16*)(ws + OFF_WFPB);
  u16*   Vcb   = (u16*)(ws + OFF_VCB);
  u16*   Vpb   = (u16*)(ws + OFF_VPB);
  u16*   W1Tp  = (u16*)(ws + OFF_W1TP);
  u16*   W1Tu  = (u16*)(ws + OFF_W1TU);
  u16*   W1pk  = (u16*)(ws + OFF_W1PK);
  u16*   W2pk  = (u16*)(ws + OFF_W2PK);
  u16*   KWc   = (u16*)(ws + OFF_KW);
  u16*   KWp   = KWc + (size_t)NC * PP;
  u16*   VW1p  = (u16*)(ws + OFF_VW1);
  u16*   VW1u  = VW1p + (size_t)SLOT * NC;
  float* sb    = (float*)(ws + OFF_SB);
  float* t0    = (float*)(ws + OFF_T);
  float* t1    = t0 + (size_t)BB * SLOT;
  float* sc    = (float*)(ws + OFF_SC);
  u16*   Pb    = (u16*)(ws + OFF_P);

  // 1) all prep in one dispatch
  prep_all<<<dim3(6592), 256, 0, stream>>>(
      inst, Kc, Kp, Wfc, Wfp, Vc, Vp, pW1, uW1, pW2, uW2, bfc, bfp,
      instb, Kcb, Kpb, Wfcb, Wfpb, Vcb, Vpb, W1Tp, W1Tu, W1pk, W2pk, sb);

  // 2) KW = K @ Wf^T  and  VW1 = (W1part^T) @ V^T in one dispatch
  gemm_mixed<<<dim3(64), 256, 0, stream>>>(
      Kcb, Kpb, Wfcb, Wfpb, KWc, KWp, W1Tp, W1Tu, Vcb, Vpb, VW1p, VW1u);

  // 3) scores = inst @ KW^T -> f32 [2][4096][512]
  gemm_scores<<<dim3(32, 4, 2), 256, 0, stream>>>(instb, KWc, KWp, sc);

  // 4) P = softmax((sc+sb)*alpha) -> bf16
  softmax_rows<<<dim3(2048), 256, 0, stream>>>(sc, sb, Pb);

  // 5) t = P @ VW1 + b1 -> f32 [2][4096][256]
  gemm_t<<<dim3(32, 2, 2), 256, 0, stream>>>(Pb, VW1p, VW1u, pb1, ub1, t0, t1);

  // 6) fused back half (512 blocks x 1024 threads, branch-split waves)
  fused_update<<<dim3(512), 1024, 0, stream>>>(
      slots, t0, t1, W1pk, W2pk, pg, pbt, ug, ubt, pb2, ub2, out);

  (void)in_sizes; (void)n_in; (void)out_size; (void)ws_size;
}

// Round 7
// 107.555 us; speedup vs baseline: 1.8315x; 1.0557x over previous
//
#include <hip/hip_runtime.h>
#include <stdint.h>

#define BB    4096
#define KS    8
#define PP    768
#define SLOT  256
#define HID   256
#define NC    512
#define BKROWS (BB*KS)          // 32768
typedef unsigned short u16;
typedef short bf16x8 __attribute__((ext_vector_type(8)));
typedef float f32x4  __attribute__((ext_vector_type(4)));

__device__ __forceinline__ u16 f2bf(float x) {
  union { float f; uint32_t u; } v; v.f = x;
  return (u16)((v.u + 0x7FFFu + ((v.u >> 16) & 1u)) >> 16);
}

__device__ __forceinline__ void gload_lds16(u16* ldst, const u16* gsrc) {
  __builtin_amdgcn_global_load_lds(
      (const __attribute__((address_space(1))) void*)gsrc,
      (__attribute__((address_space(3))) void*)ldst, 16, 0, 0);
}

// ---------------------------------------------------------------------------
// Generic GEMM core: C[M,N] = A_bf16[M,K] @ Bt_bf16[N,K]^T (+ epilogue)
// BM=BN=128, BK=64, 4 waves. EPI: 0=f32, 2=bf16, 3=+bias f32  [verified R1-R6]
// ---------------------------------------------------------------------------
template<int EPI>
__device__ __forceinline__ void gemm_core(
    const u16* __restrict__ A, int lda,
    const u16* __restrict__ B, int ldb,
    const float* __restrict__ bias,
    void* __restrict__ out, int ldo, int K,
    int blockRow, int blockCol, u16* lsA, u16* lsB)
{
  const int tid  = threadIdx.x;
  const int w    = tid >> 6;
  const int lane = tid & 63;
  const int wm   = w >> 1, wn = w & 1;
  const int rl   = lane >> 4, cl = lane & 15;

  f32x4 acc[4][4];
  const f32x4 zero = {0.f, 0.f, 0.f, 0.f};
#pragma unroll
  for (int i = 0; i < 4; ++i)
#pragma unroll
    for (int j = 0; j < 4; ++j) acc[i][j] = zero;

  const u16* Ablk = A + (size_t)blockRow * lda;
  const u16* Bblk = B + (size_t)blockCol * ldb;

  for (int k0 = 0; k0 < K; k0 += 64) {
#pragma unroll
    for (int i = 0; i < 4; ++i) {
      int seg   = i * 4 + w;
      int off16 = seg * 64 + lane;
      int row   = off16 >> 3;
      int chunk = (off16 & 7) ^ (row & 7);
      gload_lds16(lsA + seg * 512, Ablk + (size_t)row * lda + k0 + chunk * 8);
      gload_lds16(lsB + seg * 512, Bblk + (size_t)row * ldb + k0 + chunk * 8);
    }
    __syncthreads();

#pragma unroll
    for (int ks = 0; ks < 2; ++ks) {
      bf16x8 aF[4], bF[4];
#pragma unroll
      for (int f = 0; f < 4; ++f) {
        int r  = wm * 64 + f * 16 + cl;
        int ca = ((ks * 4 + rl) ^ (r & 7)) * 8;
        aF[f] = *(const bf16x8*)(lsA + r * 64 + ca);
        int rn = wn * 64 + f * 16 + cl;
        int cb = ((ks * 4 + rl) ^ (rn & 7)) * 8;
        bF[f] = *(const bf16x8*)(lsB + rn * 64 + cb);
      }
#pragma unroll
      for (int fm = 0; fm < 4; ++fm)
#pragma unroll
        for (int fn = 0; fn < 4; ++fn)
          acc[fm][fn] = __builtin_amdgcn_mfma_f32_16x16x32_bf16(
              aF[fm], bF[fn], acc[fm][fn], 0, 0, 0);
    }
    __syncthreads();
  }

#pragma unroll
  for (int fm = 0; fm < 4; ++fm) {
#pragma unroll
    for (int fn = 0; fn < 4; ++fn) {
      f32x4 v = acc[fm][fn];
#pragma unroll
      for (int r = 0; r < 4; ++r) {
        int grow = blockRow + wm * 64 + fm * 16 + rl * 4 + r;
        int gcol = blockCol + wn * 64 + fn * 16 + cl;
        float x = v[r];
        if constexpr (EPI == 0) {
          ((float*)out)[(size_t)grow * ldo + gcol] = x;
        } else if constexpr (EPI == 2) {
          ((u16*)out)[(size_t)grow * ldo + gcol] = f2bf(x);
        } else if constexpr (EPI == 3) {
          x += bias[gcol];
          ((float*)out)[(size_t)grow * ldo + gcol] = x;
        }
      }
    }
  }
}

// ---------------------------------------------------------------------------
// prep_all: one dispatch for every cvt / transpose / frag-pack / sb gemv.
// ---------------------------------------------------------------------------
__device__ __forceinline__ void cvt_seg(const float* __restrict__ in,
                                        u16* __restrict__ outp, int b, int n4) {
  int i = b * 256 + threadIdx.x;
  if (i < n4) {
    float4 v = ((const float4*)in)[i];
    ushort4 o;
    o.x = f2bf(v.x); o.y = f2bf(v.y); o.z = f2bf(v.z); o.w = f2bf(v.w);
    ((ushort4*)outp)[i] = o;
  }
}

// frag-pack: dst[((br*16+ng)*8+step)*64 + lane][j] = src[step*32 + rl*8 + j][ng*16 + cl]
__device__ __forceinline__ void pack_seg(const float* __restrict__ s0,
                                         const float* __restrict__ s1,
                                         u16* __restrict__ dst, int b) {
  int br = b >> 4, ng = b & 15;
  const float* src = br ? s1 : s0;
  int w = threadIdx.x >> 6, lane = threadIdx.x & 63;
  int rl = lane >> 4, cl = lane & 15;
#pragma unroll
  for (int s = 0; s < 2; ++s) {
    int step = w * 2 + s;
    union { u16 u[8]; uint4 q; } o;
#pragma unroll
    for (int j = 0; j < 8; ++j)
      o.u[j] = f2bf(src[(size_t)(step * 32 + rl * 8 + j) * 256 + ng * 16 + cl]);
    *(uint4*)(dst + (size_t)(((br * 16 + ng) * 8 + step) * 64 + lane) * 8) = o.q;
  }
}

__global__ __launch_bounds__(256) void prep_all(
    const float* __restrict__ inst, const float* __restrict__ Kc,
    const float* __restrict__ Kp, const float* __restrict__ Wfc,
    const float* __restrict__ Wfp, const float* __restrict__ Vc,
    const float* __restrict__ Vp, const float* __restrict__ pW1,
    const float* __restrict__ uW1, const float* __restrict__ pW2,
    const float* __restrict__ uW2, const float* __restrict__ bfc,
    const float* __restrict__ bfp,
    u16* instb, u16* Kcb, u16* Kpb, u16* Wfcb, u16* Wfpb, u16* Vcb, u16* Vpb,
    u16* W1Tp, u16* W1Tu, u16* W1pk, u16* W2pk, float* sb)
{
  __shared__ float tile[32][33];
  int b = blockIdx.x;
  if (b < 3072)      { cvt_seg(inst, instb, b,        786432); return; }
  else if (b < 3456) { cvt_seg(Kc,   Kcb,   b - 3072,  98304); return; }
  else if (b < 3840) { cvt_seg(Kp,   Kpb,   b - 3456,  98304); return; }
  else if (b < 4416) { cvt_seg(Wfc,  Wfcb,  b - 3840, 147456); return; }
  else if (b < 4992) { cvt_seg(Wfp,  Wfpb,  b - 4416, 147456); return; }
  else if (b < 5376) { cvt_seg(Vc,   Vcb,   b - 4992,  98304); return; }
  else if (b < 5760) { cvt_seg(Vp,   Vpb,   b - 5376,  98304); return; }
  else if (b < 6272) {
    // transpose [1024][256] f32 -> [256][1024] bf16
    int bb = b - 5760;
    const float* in = (bb < 256) ? pW1 : uW1;
    u16* outp = (bb < 256) ? W1Tp : W1Tu;
    bb &= 255;
    int tc = (bb & 7) * 32, tr = (bb >> 3) * 32;
    int lx = threadIdx.x & 31, ly = threadIdx.x >> 5;
#pragma unroll
    for (int i = 0; i < 32; i += 8)
      tile[ly + i][lx] = in[(size_t)(tr + ly + i) * 256 + tc + lx];
    __syncthreads();
#pragma unroll
    for (int i = 0; i < 32; i += 8)
      outp[(size_t)(tc + ly + i) * 1024 + tr + lx] = f2bf(tile[lx][ly + i]);
    return;
  }
  else if (b < 6304) { pack_seg(pW1, uW1, W1pk, b - 6272); return; }
  else if (b < 6336) { pack_seg(pW2, uW2, W2pk, b - 6304); return; }
  else {
    int w = threadIdx.x >> 6, lane = threadIdx.x & 63;
    int row = (b - 6336) * 4 + w;
    int br = row >> 9, n = row & 511;
    const float* Kr = (br ? Kp : Kc) + (size_t)n * PP;
    const float* bf = br ? bfp : bfc;
    float s = 0.f;
#pragma unroll
    for (int j = 0; j < 12; ++j) s += Kr[lane + j * 64] * bf[lane + j * 64];
#pragma unroll
    for (int o = 32; o; o >>= 1) s += __shfl_xor(s, o);
    if (!lane) sb[row] = s;
  }
}

// ---------------------------------------------------------------------------
// merged small GEMMs
// ---------------------------------------------------------------------------
__global__ __launch_bounds__(256) void gemm_mixed(
    const u16* Kcb, const u16* Kpb, const u16* Wfcb, const u16* Wfpb,
    u16* KWc, u16* KWp,
    const u16* W1Tp, const u16* W1Tu, const u16* Vcb, const u16* Vpb,
    u16* VW1p, u16* VW1u)
{
  __shared__ u16 lsA[128 * 64];
  __shared__ u16 lsB[128 * 64];
  int b = blockIdx.x;
  if (b < 48) {
    int z = b / 24, r = b % 24;
    gemm_core<2>(z ? Kpb : Kcb, PP, z ? Wfpb : Wfcb, PP, nullptr,
                 z ? KWp : KWc, PP, PP, (r & 3) * 128, (r >> 2) * 128, lsA, lsB);
  } else {
    int c = b - 48, z = c / 8, r = c % 8;
    gemm_core<2>((z ? W1Tu : W1Tp) + 256, 1024, z ? Vpb : Vcb, PP, nullptr,
                 z ? VW1u : VW1p, NC, PP, (r & 1) * 128, (r >> 1) * 128, lsA, lsB);
  }
}

__global__ __launch_bounds__(256) void gemm_scores(
    const u16* instb, const u16* KWc, const u16* KWp, float* sc)
{
  __shared__ u16 lsA[128 * 64];
  __shared__ u16 lsB[128 * 64];
  int z = blockIdx.z;
  gemm_core<0>(instb, PP, z ? KWp : KWc, PP, nullptr,
               sc + (size_t)z * BB * NC, NC, PP,
               blockIdx.x * 128, blockIdx.y * 128, lsA, lsB);
}

__global__ __launch_bounds__(256) void gemm_t(
    const u16* Pb, const u16* VW1p, const u16* VW1u,
    const float* pb1, const float* ub1, float* t0, float* t1)
{
  __shared__ u16 lsA[128 * 64];
  __shared__ u16 lsB[128 * 64];
  int z = blockIdx.z;
  gemm_core<3>(Pb + (size_t)z * BB * NC, NC, z ? VW1u : VW1p, NC,
               z ? ub1 : pb1, z ? t1 : t0, SLOT, NC,
               blockIdx.x * 128, blockIdx.y * 128, lsA, lsB);
}

// ---------------------------------------------------------------------------
// softmax over rows of 512 with broadcast bias sb[n]; alpha folded
// ---------------------------------------------------------------------------
__global__ __launch_bounds__(256) void softmax_rows(const float* __restrict__ S,
                                                    const float* __restrict__ sb,
                                                    u16* __restrict__ Pp) {
  int w = threadIdx.x >> 6, lane = threadIdx.x & 63;
  size_t row = (size_t)blockIdx.x * 4 + w;
  const float* src = S + row * 512 + lane * 8;
  const float* sbr = sb + ((row >> 12) << 9) + lane * 8;
  float4 v0 = *(const float4*)src;
  float4 v1 = *(const float4*)(src + 4);
  float4 s0 = *(const float4*)sbr;
  float4 s1 = *(const float4*)(sbr + 4);
  float vv[8] = {v0.x + s0.x, v0.y + s0.y, v0.z + s0.z, v0.w + s0.w,
                 v1.x + s1.x, v1.y + s1.y, v1.z + s1.z, v1.w + s1.w};
  float m = vv[0];
#pragma unroll
  for (int j = 1; j < 8; ++j) m = fmaxf(m, vv[j]);
#pragma unroll
  for (int o = 32; o; o >>= 1) m = fmaxf(m, __shfl_xor(m, o));
  const float alpha = 0.03608439182435161f;   // 1/sqrt(768)
  float e[8], s = 0.f;
#pragma unroll
  for (int j = 0; j < 8; ++j) { e[j] = __expf((vv[j] - m) * alpha); s += e[j]; }
#pragma unroll
  for (int o = 32; o; o >>= 1) s += __shfl_xor(s, o);
  float inv = 1.f / s;
  union { u16 u[8]; uint4 q; } ou;
#pragma unroll
  for (int j = 0; j < 8; ++j) ou.u[j] = f2bf(e[j] * inv);
  *(uint4*)(Pp + row * 512 + lane * 8) = ou.q;
}

// ---------------------------------------------------------------------------
// FUSED back half v5: 32 rows/block, 1024 blocks, 512 threads = 8 waves.
// GEMM1: every wave does BOTH branches on cols [w*32,w*32+32)  (acc 32 regs).
// GEMM2: waves re-split: branch = w>>2, cols [(w&3)*64, +64)   (acc 32 regs).
// Dual 16KB H tiles (P->lsH[0] over dead slots tile, U->lsH[1]) so both
// branch GEMM2s run concurrently with no barrier between them.
// Gate exchange through the (dead) H LDS region as f32. 6 barriers.
// LDS ~37KB -> 4 blocks/CU capacity; 1024 blocks give block-level churn.
// ---------------------------------------------------------------------------
__global__ __launch_bounds__(512, 4) void fused_update(
    const float* __restrict__ slots,
    const float* __restrict__ t0, const float* __restrict__ t1,
    const u16* __restrict__ W1pk, const u16* __restrict__ W2pk,
    const float* __restrict__ pg, const float* __restrict__ pbt,
    const float* __restrict__ ug, const float* __restrict__ ubt,
    const float* __restrict__ pb2, const float* __restrict__ ub2,
    float* __restrict__ outp)
{
  __shared__ u16 lsH[2][32 * 256];     // 2 x 16KB: [0] slots->Hp, [1] Hu; xchg f32
  __shared__ float lstat[2][32][16];   // 4KB: [br][row][w]=sum, [8+w]=sumsq
  __shared__ float lfin[2][32][2];     // mean/rstd

  const int tid = threadIdx.x, w = tid >> 6, lane = tid & 63;
  const int rl = lane >> 4, cl = lane & 15;
  const int blockRow = blockIdx.x * 32;

  u16* lsA = lsH[0];

  // --- stage slots f32 -> bf16 into lsA, swizzled (16B-chunk ^= row&7)
#pragma unroll
  for (int it = 0; it < 4; ++it) {
    int L = it * 512 + tid;           // float4 index in [0,2048)
    int row = L >> 6, qc = L & 63;
    float4 v = *(const float4*)(slots + (size_t)(blockRow + row) * 256 + qc * 4);
    ushort4 b; b.x = f2bf(v.x); b.y = f2bf(v.y); b.z = f2bf(v.z); b.w = f2bf(v.w);
    int chunk = qc >> 1, half = qc & 1;
    *(ushort4*)(lsA + row * 256 + (((chunk ^ (row & 7)) << 3) + half * 4)) = b;
  }
  __syncthreads();                                   // B1

  f32x4 acc[2][4];                    // GEMM1: [fm][br*2+fn]; GEMM2: [fm][fn]
  const f32x4 zero = {0.f, 0.f, 0.f, 0.f};
#pragma unroll
  for (int i = 0; i < 2; ++i)
#pragma unroll
    for (int j = 0; j < 4; ++j) acc[i][j] = zero;

  // --- GEMM1: K=256 (8 steps of 32), A from LDS, B from L2, both branches
#pragma unroll
  for (int step = 0; step < 8; ++step) {
    bf16x8 aF[2], bP[2], bU[2];
#pragma unroll
    for (int f = 0; f < 2; ++f) {
      int row = f * 16 + cl;
      aF[f] = *(const bf16x8*)(lsA + row * 256 + (((step * 4 + rl) ^ (row & 7)) << 3));
      int ng = w * 2 + f;
      bP[f] = *(const bf16x8*)(W1pk + (size_t)((ng * 8 + step) * 64 + lane) * 8);
      bU[f] = *(const bf16x8*)(W1pk + (size_t)(((16 + ng) * 8 + step) * 64 + lane) * 8);
    }
#pragma unroll
    for (int fm = 0; fm < 2; ++fm)
#pragma unroll
      for (int fn = 0; fn < 2; ++fn) {
        acc[fm][fn]     = __builtin_amdgcn_mfma_f32_16x16x32_bf16(aF[fm], bP[fn], acc[fm][fn], 0, 0, 0);
        acc[fm][2 + fn] = __builtin_amdgcn_mfma_f32_16x16x32_bf16(aF[fm], bU[fn], acc[fm][2 + fn], 0, 0, 0);
      }
  }

  // --- t add (b1 folded into t)
#pragma unroll
  for (int fm = 0; fm < 2; ++fm) {
    size_t trr = (size_t)(blockIdx.x * 4 + fm * 2 + (rl >> 1)) * 256;
#pragma unroll
    for (int fn = 0; fn < 2; ++fn) {
      int col = w * 32 + fn * 16 + cl;
      float tp = t0[trr + col], tu = t1[trr + col];
#pragma unroll
      for (int r = 0; r < 4; ++r) {
        acc[fm][fn][r]     += tp;
        acc[fm][2 + fn][r] += tu;
      }
    }
  }

  // --- LN partial stats: in-reg over fn, butterfly over cl, LDS over w
#pragma unroll
  for (int fm = 0; fm < 2; ++fm)
#pragma unroll
    for (int br = 0; br < 2; ++br) {
      f32x4 s = acc[fm][br * 2] + acc[fm][br * 2 + 1];
      f32x4 q = acc[fm][br * 2] * acc[fm][br * 2] + acc[fm][br * 2 + 1] * acc[fm][br * 2 + 1];
#pragma unroll
      for (int o = 1; o < 16; o <<= 1) {
#pragma unroll
        for (int r = 0; r < 4; ++r) {
          s[r] += __shfl_xor(s[r], o);
          q[r] += __shfl_xor(q[r], o);
        }
      }
      if (cl == 0) {
#pragma unroll
        for (int r = 0; r < 4; ++r) {
          int row = fm * 16 + rl * 4 + r;
          lstat[br][row][w]     = s[r];
          lstat[br][row][8 + w] = q[r];
        }
      }
    }
  __syncthreads();                                   // B2

  // --- finalize stats: 64 threads handle (br,row)
  if (tid < 64) {
    int fb = tid >> 5, row = tid & 31;
    f32x4 a = *(const f32x4*)&lstat[fb][row][0];
    f32x4 b = *(const f32x4*)&lstat[fb][row][4];
    f32x4 c = *(const f32x4*)&lstat[fb][row][8];
    f32x4 d = *(const f32x4*)&lstat[fb][row][12];
    float ss = a[0] + a[1] + a[2] + a[3] + b[0] + b[1] + b[2] + b[3];
    float qq = c[0] + c[1] + c[2] + c[3] + d[0] + d[1] + d[2] + d[3];
    float mu = ss * (1.f / 256.f);
    lfin[fb][row][0] = mu;
    lfin[fb][row][1] = rsqrtf(qq * (1.f / 256.f) - mu * mu + 1e-5f);
  }
  __syncthreads();                                   // B2b

  // --- normalize both branches -> H tiles (P: lsH[0] over dead slots, U: lsH[1])
  {
    float gv[2][2], btv[2][2];
#pragma unroll
    for (int fn = 0; fn < 2; ++fn) {
      int col = w * 32 + fn * 16 + cl;
      gv[0][fn] = pg[col];  btv[0][fn] = pbt[col];
      gv[1][fn] = ug[col];  btv[1][fn] = ubt[col];
    }
#pragma unroll
    for (int fm = 0; fm < 2; ++fm) {
      float mean[2][4], rstd[2][4];
#pragma unroll
      for (int r = 0; r < 4; ++r) {
        int row = fm * 16 + rl * 4 + r;
        mean[0][r] = lfin[0][row][0]; rstd[0][r] = lfin[0][row][1];
        mean[1][r] = lfin[1][row][0]; rstd[1][r] = lfin[1][row][1];
      }
#pragma unroll
      for (int br = 0; br < 2; ++br)
#pragma unroll
        for (int fn = 0; fn < 2; ++fn) {
          int col = w * 32 + fn * 16 + cl;
#pragma unroll
          for (int r = 0; r < 4; ++r) {
            int row = fm * 16 + rl * 4 + r;
            float h = fmaxf((acc[fm][br * 2 + fn][r] - mean[br][r]) * rstd[br][r]
                            * gv[br][fn] + btv[br][fn], 0.f);
            lsH[br][row * 256 + (((col >> 3) ^ (row & 7)) << 3) + (col & 7)] = f2bf(h);
          }
        }
    }
  }
  // reset acc for GEMM2
#pragma unroll
  for (int i = 0; i < 2; ++i)
#pragma unroll
    for (int j = 0; j < 4; ++j) acc[i][j] = zero;
  __syncthreads();                                   // B3 (H tiles visible)

  // --- GEMM2: branch-parallel. brw = w>>2; cols [(w&3)*64, +64)
  const int brw = w >> 2, wc = w & 3;
  const u16* hsrc = lsH[brw];
  const float* b2src = brw ? ub2 : pb2;
  float b2v[4];
#pragma unroll
  for (int fn = 0; fn < 4; ++fn) b2v[fn] = b2src[wc * 64 + fn * 16 + cl];

#pragma unroll
  for (int step = 0; step < 8; ++step) {
    bf16x8 aF[2], bF[4];
#pragma unroll
    for (int f = 0; f < 2; ++f) {
      int row = f * 16 + cl;
      aF[f] = *(const bf16x8*)(hsrc + row * 256 + (((step * 4 + rl) ^ (row & 7)) << 3));
    }
#pragma unroll
    for (int f = 0; f < 4; ++f) {
      int ng = wc * 4 + f;
      bF[f] = *(const bf16x8*)(W2pk + (size_t)(((brw * 16 + ng) * 8 + step) * 64 + lane) * 8);
    }
#pragma unroll
    for (int fm = 0; fm < 2; ++fm)
#pragma unroll
      for (int fn = 0; fn < 4; ++fn)
        acc[fm][fn] = __builtin_amdgcn_mfma_f32_16x16x32_bf16(aF[fm], bF[fn], acc[fm][fn], 0, 0, 0);
  }
  __syncthreads();                                   // B4 (all H reads done)

  // --- gate exchange: P waves write gp into xbuf (32KB spanning both H tiles)
  float* xbuf = (float*)&lsH[0][0];
  const int base = wc * 2048;
  if (brw == 0) {
#pragma unroll
    for (int fm = 0; fm < 2; ++fm)
#pragma unroll
      for (int fn = 0; fn < 4; ++fn)
#pragma unroll
        for (int r = 0; r < 4; ++r)
          xbuf[base + ((fm * 4 + fn) * 4 + r) * 64 + lane] = acc[fm][fn][r] + b2v[fn];
  }
  __syncthreads();                                   // B5

  // --- U waves combine: out = slots + gp*gu
  if (brw == 1) {
#pragma unroll
    for (int fm = 0; fm < 2; ++fm)
#pragma unroll
      for (int fn = 0; fn < 4; ++fn)
#pragma unroll
        for (int r = 0; r < 4; ++r) {
          float gp = xbuf[base + ((fm * 4 + fn) * 4 + r) * 64 + lane];
          float gu = acc[fm][fn][r] + b2v[fn];
          int row = blockRow + fm * 16 + rl * 4 + r;
          int col = wc * 64 + fn * 16 + cl;
          size_t idx = (size_t)row * 256 + col;
          outp[idx] = slots[idx] + gp * gu;
        }
  }
}

// ---------------------------------------------------------------------------
// host launcher
// ---------------------------------------------------------------------------
extern "C" void kernel_launch(void* const* d_in, const int* in_sizes, int n_in,
                              void* d_out, int out_size, void* d_ws, size_t ws_size,
                              hipStream_t stream) {
  const float* inst  = (const float*)d_in[0];
  const float* slots = (const float*)d_in[1];
  const float* Wfc   = (const float*)d_in[2];
  const float* bfc   = (const float*)d_in[3];
  const float* Wfp   = (const float*)d_in[4];
  const float* bfp   = (const float*)d_in[5];
  const float* Kc    = (const float*)d_in[6];
  const float* Vc    = (const float*)d_in[7];
  const float* Kp    = (const float*)d_in[8];
  const float* Vp    = (const float*)d_in[9];
  const float* pW1   = (const float*)d_in[10];
  const float* pb1   = (const float*)d_in[11];
  const float* pg    = (const float*)d_in[12];
  const float* pbt   = (const float*)d_in[13];
  const float* pW2   = (const float*)d_in[14];
  const float* pb2   = (const float*)d_in[15];
  const float* uW1   = (const float*)d_in[16];
  const float* ub1   = (const float*)d_in[17];
  const float* ug    = (const float*)d_in[18];
  const float* ubt   = (const float*)d_in[19];
  const float* uW2   = (const float*)d_in[20];
  const float* ub2   = (const float*)d_in[21];
  float* out = (float*)d_out;
  char*  ws  = (char*)d_ws;

  // ---- workspace layout (bytes) ----
  const size_t OFF_INST  = 0;                         // [4096][768] bf16
  const size_t OFF_KC    = OFF_INST  + 6291456;       // [512][768] bf16 x2
  const size_t OFF_KP    = OFF_KC    + 786432;
  const size_t OFF_WFCB  = OFF_KP    + 786432;        // [768][768] bf16 x2
  const size_t OFF_WFPB  = OFF_WFCB  + 1179648;
  const size_t OFF_VCB   = OFF_WFPB  + 1179648;       // [512][768] bf16 x2
  const size_t OFF_VPB   = OFF_VCB   + 786432;
  const size_t OFF_W1TP  = OFF_VPB   + 786432;        // [256][1024] bf16 x2
  const size_t OFF_W1TU  = OFF_W1TP  + 524288;
  const size_t OFF_W1PK  = OFF_W1TU  + 524288;        // [2][16][8][64][8] bf16
  const size_t OFF_W2PK  = OFF_W1PK  + 262144;
  const size_t OFF_KW    = OFF_W2PK  + 262144;        // [2][512][768] bf16
  const size_t OFF_VW1   = OFF_KW    + 1572864;       // [2][256][512] bf16
  const size_t OFF_SB    = OFF_VW1   + 524288;        // [2][512] f32
  const size_t OFF_T     = OFF_SB    + 4096;          // [2][4096][256] f32
  const size_t OFF_SC    = OFF_T     + 8388608;       // [2][4096][512] f32
  const size_t OFF_P     = OFF_SC    + 16777216;      // [2][4096][512] bf16

  u16*   instb = (u16*)(ws + OFF_INST);
  u16*   Kcb   = (u16*)(ws + OFF_KC);
  u16*   Kpb   = (u16*)(ws + OFF_KP);
  u16*   Wfcb  = (u16*)(ws + OFF_WFCB);
  u16*   Wfpb  = (u16*)(ws + OFF_WFPB);
  u16*   Vcb   = (u16*)(ws + OFF_VCB);
  u16*   Vpb   = (u16*)(ws + OFF_VPB);
  u16*   W1Tp  = (u16*)(ws + OFF_W1TP);
  u16*   W1Tu  = (u16*)(ws + OFF_W1TU);
  u16*   W1pk  = (u16*)(ws + OFF_W1PK);
  u16*   W2pk  = (u16*)(ws + OFF_W2PK);
  u16*   KWc   = (u16*)(ws + OFF_KW);
  u16*   KWp   = KWc + (size_t)NC * PP;
  u16*   VW1p  = (u16*)(ws + OFF_VW1);
  u16*   VW1u  = VW1p + (size_t)SLOT * NC;
  float* sb    = (float*)(ws + OFF_SB);
  float* t0    = (float*)(ws + OFF_T);
  float* t1    = t0 + (size_t)BB * SLOT;
  float* sc    = (float*)(ws + OFF_SC);
  u16*   Pb    = (u16*)(ws + OFF_P);

  // 1) all prep in one dispatch
  prep_all<<<dim3(6592), 256, 0, stream>>>(
      inst, Kc, Kp, Wfc, Wfp, Vc, Vp, pW1, uW1, pW2, uW2, bfc, bfp,
      instb, Kcb, Kpb, Wfcb, Wfpb, Vcb, Vpb, W1Tp, W1Tu, W1pk, W2pk, sb);

  // 2) KW = K @ Wf^T  and  VW1 = (W1part^T) @ V^T in one dispatch
  gemm_mixed<<<dim3(64), 256, 0, stream>>>(
      Kcb, Kpb, Wfcb, Wfpb, KWc, KWp, W1Tp, W1Tu, Vcb, Vpb, VW1p, VW1u);

  // 3) scores = inst @ KW^T -> f32 [2][4096][512]
  gemm_scores<<<dim3(32, 4, 2), 256, 0, stream>>>(instb, KWc, KWp, sc);

  // 4) P = softmax((sc+sb)*alpha) -> bf16
  softmax_rows<<<dim3(2048), 256, 0, stream>>>(sc, sb, Pb);

  // 5) t = P @ VW1 + b1 -> f32 [2][4096][256]
  gemm_t<<<dim3(32, 2, 2), 256, 0, stream>>>(Pb, VW1p, VW1u, pb1, ub1, t0, t1);

  // 6) fused back half (1024 blocks x 512 threads, 32 rows each)
  fused_update<<<dim3(1024), 512, 0, stream>>>(
      slots, t0, t1, W1pk, W2pk, pg, pbt, ug, ubt, pb2, ub2, out);

  (void)in_sizes; (void)n_in; (void)out_size; (void)ws_size;
}